// Round 1
// baseline (1732.291 us; speedup 1.0000x reference)
//
#include <hip/hip_runtime.h>
#include <cmath>

// ---------------------------------------------------------------------------
// MemoryBankV2: B=128, T=32, D=512, L=2.  Rows = B*T = 4096.
// Round 0: all-f32 tiled vector-ALU implementation (correctness baseline).
// GEMM shapes are all "A[M,K] @ B[N,K]^T" (weights stored [N,K] row-major),
// except attn a@v which is A[M,K] @ V[K,N].
// ---------------------------------------------------------------------------

#define ROWS 4096
#define DIM  512

// ---------------- GEMM: C[M,N] = epi(A[M,K] @ B[N,K]^T (+ bias)) ------------
// EPI: 0 = +bias; 1 = gelu(x + bias) exact; 2 = *scale (no bias)
// SKIP: skip tiles with n0 > m0 (block-causal score GEMM)
template<int EPI, bool SKIP>
__global__ __launch_bounds__(256)
void gemm_bt(const float* __restrict__ A, const float* __restrict__ B,
             const float* __restrict__ bias, float* __restrict__ C,
             int M, int N, int K, float scale)
{
    const int m0 = blockIdx.x * 64;
    const int n0 = blockIdx.y * 64;
    if (SKIP && n0 > m0) return;

    __shared__ float As[16][68];   // [k][m], pad 68 keeps float4 16B-aligned
    __shared__ float Bs[16][68];   // [k][n]

    const int tid = threadIdx.x;
    const int tx  = tid & 15;
    const int ty  = tid >> 4;
    const int lr  = tid >> 2;          // 0..63 tile row for staging
    const int lk  = (tid & 3) << 2;    // 0,4,8,12

    float acc[4][4] = {};

    for (int k0 = 0; k0 < K; k0 += 16) {
        const float4 a4 = *reinterpret_cast<const float4*>(&A[(size_t)(m0 + lr) * K + k0 + lk]);
        const float4 b4 = *reinterpret_cast<const float4*>(&B[(size_t)(n0 + lr) * K + k0 + lk]);
        As[lk + 0][lr] = a4.x; As[lk + 1][lr] = a4.y; As[lk + 2][lr] = a4.z; As[lk + 3][lr] = a4.w;
        Bs[lk + 0][lr] = b4.x; Bs[lk + 1][lr] = b4.y; Bs[lk + 2][lr] = b4.z; Bs[lk + 3][lr] = b4.w;
        __syncthreads();
        #pragma unroll
        for (int kk = 0; kk < 16; ++kk) {
            const float4 av = *reinterpret_cast<const float4*>(&As[kk][ty << 2]);
            const float4 bv = *reinterpret_cast<const float4*>(&Bs[kk][tx << 2]);
            const float a[4] = {av.x, av.y, av.z, av.w};
            const float b[4] = {bv.x, bv.y, bv.z, bv.w};
            #pragma unroll
            for (int i = 0; i < 4; ++i)
                #pragma unroll
                for (int j = 0; j < 4; ++j)
                    acc[i][j] = fmaf(a[i], b[j], acc[i][j]);
        }
        __syncthreads();
    }

    #pragma unroll
    for (int i = 0; i < 4; ++i) {
        const int row = m0 + (ty << 2) + i;
        #pragma unroll
        for (int j = 0; j < 4; ++j) {
            const int col = n0 + (tx << 2) + j;
            float v = acc[i][j];
            if (EPI == 0 || EPI == 1) v += bias[col];
            if (EPI == 1) v = 0.5f * v * (1.0f + erff(v * 0.70710678118654752f));
            if (EPI == 2) v *= scale;
            C[(size_t)row * N + col] = v;
        }
    }
}

// ---------------- masked row softmax (in place) -----------------------------
// row i belongs to batch item b = i>>5; valid memory entries m < b*32.
// b==0 rows are skipped entirely (their whole transformer path is discarded).
__global__ __launch_bounds__(256)
void softmax_rows(float* __restrict__ S, int Kfull)
{
    const int row = blockIdx.x;
    const int b = row >> 5;
    if (b == 0) return;
    const int Lb = b << 5;
    float* srow = S + (size_t)row * Kfull;
    __shared__ float red[4];

    float mx = -3.0e38f;
    for (int m = threadIdx.x; m < Lb; m += 256) mx = fmaxf(mx, srow[m]);
    #pragma unroll
    for (int off = 32; off; off >>= 1) mx = fmaxf(mx, __shfl_xor(mx, off));
    if ((threadIdx.x & 63) == 0) red[threadIdx.x >> 6] = mx;
    __syncthreads();
    mx = fmaxf(fmaxf(red[0], red[1]), fmaxf(red[2], red[3]));
    __syncthreads();

    float sum = 0.0f;
    for (int m = threadIdx.x; m < Lb; m += 256) {
        const float e = expf(srow[m] - mx);
        srow[m] = e;
        sum += e;
    }
    #pragma unroll
    for (int off = 32; off; off >>= 1) sum += __shfl_xor(sum, off);
    if ((threadIdx.x & 63) == 0) red[threadIdx.x >> 6] = sum;
    __syncthreads();
    sum = red[0] + red[1] + red[2] + red[3];
    const float inv = 1.0f / sum;
    for (int m = threadIdx.x; m < Lb; m += 256) srow[m] *= inv;
}

// ---------------- attn out: C[32,512] per batch item = P @ V ---------------
// one row-tile = one batch item (32 rows), K bound = b*32.
__global__ __launch_bounds__(256)
void av_gemm(const float* __restrict__ P, const float* __restrict__ V,
             float* __restrict__ C)
{
    const int bb = blockIdx.x;          // batch item
    if (bb == 0) return;
    const int n0 = blockIdx.y * 64;
    const int m0 = bb << 5;
    const int Keff = bb << 5;
    constexpr int N = 512, Kfull = 4096;

    __shared__ float PsT[32][36];   // [kk][row]
    __shared__ float Vs[32][68];    // [kk][col]

    const int tid = threadIdx.x;
    const int tx = tid & 15;        // 4 cols each
    const int ty = tid >> 4;        // 2 rows each

    const int pr = tid >> 3;        // 0..31
    const int pk = (tid & 7) << 2;  // 0..28
    const int vr = tid >> 4;        // 0..15 (and +16)
    const int vc = (tid & 15) << 2;

    float acc[2][4] = {};

    for (int k0 = 0; k0 < Keff; k0 += 32) {
        const float4 p4 = *reinterpret_cast<const float4*>(&P[(size_t)(m0 + pr) * Kfull + k0 + pk]);
        PsT[pk + 0][pr] = p4.x; PsT[pk + 1][pr] = p4.y; PsT[pk + 2][pr] = p4.z; PsT[pk + 3][pr] = p4.w;
        const float4 va = *reinterpret_cast<const float4*>(&V[(size_t)(k0 + vr) * N + n0 + vc]);
        const float4 vb = *reinterpret_cast<const float4*>(&V[(size_t)(k0 + vr + 16) * N + n0 + vc]);
        Vs[vr     ][vc + 0] = va.x; Vs[vr     ][vc + 1] = va.y; Vs[vr     ][vc + 2] = va.z; Vs[vr     ][vc + 3] = va.w;
        Vs[vr + 16][vc + 0] = vb.x; Vs[vr + 16][vc + 1] = vb.y; Vs[vr + 16][vc + 2] = vb.z; Vs[vr + 16][vc + 3] = vb.w;
        __syncthreads();
        #pragma unroll
        for (int kk = 0; kk < 32; ++kk) {
            const float2 a2 = *reinterpret_cast<const float2*>(&PsT[kk][ty << 1]);
            const float4 bv = *reinterpret_cast<const float4*>(&Vs[kk][tx << 2]);
            acc[0][0] = fmaf(a2.x, bv.x, acc[0][0]);
            acc[0][1] = fmaf(a2.x, bv.y, acc[0][1]);
            acc[0][2] = fmaf(a2.x, bv.z, acc[0][2]);
            acc[0][3] = fmaf(a2.x, bv.w, acc[0][3]);
            acc[1][0] = fmaf(a2.y, bv.x, acc[1][0]);
            acc[1][1] = fmaf(a2.y, bv.y, acc[1][1]);
            acc[1][2] = fmaf(a2.y, bv.z, acc[1][2]);
            acc[1][3] = fmaf(a2.y, bv.w, acc[1][3]);
        }
        __syncthreads();
    }
    #pragma unroll
    for (int i = 0; i < 2; ++i) {
        const int row = m0 + (ty << 1) + i;
        #pragma unroll
        for (int j = 0; j < 4; ++j)
            C[(size_t)row * N + n0 + (tx << 2) + j] = acc[i][j];
    }
}

// ---------------- x = LayerNorm(x + t) * gamma + beta (one wave per row) ----
__global__ __launch_bounds__(256)
void ln_res(float* __restrict__ X, const float* __restrict__ T,
            const float* __restrict__ gamma, const float* __restrict__ beta)
{
    const int row  = blockIdx.x * 4 + (threadIdx.x >> 6);
    const int lane = threadIdx.x & 63;
    float* xr = X + (size_t)row * DIM;
    const float* tr = T + (size_t)row * DIM;
    const int d0 = lane << 3;

    const float4 x0 = *reinterpret_cast<const float4*>(&xr[d0]);
    const float4 x1 = *reinterpret_cast<const float4*>(&xr[d0 + 4]);
    const float4 t0 = *reinterpret_cast<const float4*>(&tr[d0]);
    const float4 t1 = *reinterpret_cast<const float4*>(&tr[d0 + 4]);
    float v[8] = {x0.x + t0.x, x0.y + t0.y, x0.z + t0.z, x0.w + t0.w,
                  x1.x + t1.x, x1.y + t1.y, x1.z + t1.z, x1.w + t1.w};

    float s = 0.f;
    #pragma unroll
    for (int i = 0; i < 8; ++i) s += v[i];
    #pragma unroll
    for (int off = 32; off; off >>= 1) s += __shfl_xor(s, off);
    const float mu = s * (1.0f / 512.0f);

    float q = 0.f;
    #pragma unroll
    for (int i = 0; i < 8; ++i) { const float d = v[i] - mu; q += d * d; }
    #pragma unroll
    for (int off = 32; off; off >>= 1) q += __shfl_xor(q, off);
    const float rs = rsqrtf(q * (1.0f / 512.0f) + 1e-5f);

    const float4 g0 = *reinterpret_cast<const float4*>(&gamma[d0]);
    const float4 g1 = *reinterpret_cast<const float4*>(&gamma[d0 + 4]);
    const float4 b0 = *reinterpret_cast<const float4*>(&beta[d0]);
    const float4 b1 = *reinterpret_cast<const float4*>(&beta[d0 + 4]);
    float4 o0, o1;
    o0.x = (v[0] - mu) * rs * g0.x + b0.x;
    o0.y = (v[1] - mu) * rs * g0.y + b0.y;
    o0.z = (v[2] - mu) * rs * g0.z + b0.z;
    o0.w = (v[3] - mu) * rs * g0.w + b0.w;
    o1.x = (v[4] - mu) * rs * g1.x + b1.x;
    o1.y = (v[5] - mu) * rs * g1.y + b1.y;
    o1.z = (v[6] - mu) * rs * g1.z + b1.z;
    o1.w = (v[7] - mu) * rs * g1.w + b1.w;
    *reinterpret_cast<float4*>(&xr[d0])     = o0;
    *reinterpret_cast<float4*>(&xr[d0 + 4]) = o1;
}

// ---------------- elementwise helpers ---------------------------------------
__global__ __launch_bounds__(256)
void copy_f4(float4* __restrict__ dst, const float4* __restrict__ src)
{
    const int idx = blockIdx.x * 256 + threadIdx.x;
    dst[idx] = src[idx];
}

// cat[row] = [cf[row], (row<32 ? cf : x)[row]]   (cat is [4096,1024])
__global__ __launch_bounds__(256)
void build_cat(float4* __restrict__ cat, const float4* __restrict__ cf,
               const float4* __restrict__ x)
{
    const int idx = blockIdx.x * 256 + threadIdx.x;   // 4096*256 float4
    const int row = idx >> 8;
    const int c4  = idx & 255;
    float4 v;
    if (c4 < 128) v = cf[row * 128 + c4];
    else          v = (row < 32) ? cf[row * 128 + c4 - 128] : x[row * 128 + c4 - 128];
    cat[idx] = v;
}

// out = sigmoid(glog) * cf + (1-sigmoid) * attn_out, attn_out = (b==0? cf : x)
__global__ __launch_bounds__(256)
void final_gate(float4* __restrict__ out, const float4* __restrict__ cf,
                const float4* __restrict__ x, const float4* __restrict__ glog)
{
    const int idx = blockIdx.x * 256 + threadIdx.x;   // 524288 float4
    const int row = idx >> 7;
    const float4 zc = cf[idx];
    const float4 zg = glog[idx];
    const float4 za = (row < 32) ? zc : x[idx];
    float4 o;
    {
        const float g = 1.0f / (1.0f + expf(-zg.x)); o.x = g * zc.x + (1.0f - g) * za.x;
    }
    {
        const float g = 1.0f / (1.0f + expf(-zg.y)); o.y = g * zc.y + (1.0f - g) * za.y;
    }
    {
        const float g = 1.0f / (1.0f + expf(-zg.z)); o.z = g * zc.z + (1.0f - g) * za.z;
    }
    {
        const float g = 1.0f / (1.0f + expf(-zg.w)); o.w = g * zc.w + (1.0f - g) * za.w;
    }
    out[idx] = o;
}

// ---------------------------------------------------------------------------
extern "C" void kernel_launch(void* const* d_in, const int* in_sizes, int n_in,
                              void* d_out, int out_size, void* d_ws, size_t ws_size,
                              hipStream_t stream)
{
    const float* cf   = (const float*)d_in[0];
    const float* Wq   = (const float*)d_in[1];
    const float* bq   = (const float*)d_in[2];
    const float* Wk   = (const float*)d_in[3];
    const float* bk   = (const float*)d_in[4];
    const float* Wv   = (const float*)d_in[5];
    const float* bv   = (const float*)d_in[6];
    const float* ln1g = (const float*)d_in[7];
    const float* ln1b = (const float*)d_in[8];
    const float* W1   = (const float*)d_in[9];
    const float* b1   = (const float*)d_in[10];
    const float* W2   = (const float*)d_in[11];
    const float* b2   = (const float*)d_in[12];
    const float* ln2g = (const float*)d_in[13];
    const float* ln2b = (const float*)d_in[14];
    const float* Wsg  = (const float*)d_in[15];
    const float* bsg  = (const float*)d_in[16];
    float* out = (float*)d_out;

    const size_t RD = (size_t)ROWS * DIM;        // 2,097,152
    float* ws = (float*)d_ws;
    float* x  = ws;
    float* q  = x  + RD;
    float* k  = q  + RD;
    float* v  = k  + RD;
    float* t1 = v  + RD;
    float* big = t1 + RD;        // 16,777,216 floats, time-shared: s / h / cat
    float* s   = big;            // [4096,4096] (attention phase)
    float* h   = big;            // [4096,2048] (MLP phase)
    float* cat = big;            // [4096,1024] (gate phase)
    float* glog = q;             // reuse q after last layer

    const float scale = 0.044194173824159216f;   // 1/sqrt(512)

    copy_f4<<<2048, 256, 0, stream>>>((float4*)x, (const float4*)cf);

    for (int l = 0; l < 2; ++l) {
        const float* Wq_l = Wq + (size_t)l * DIM * DIM;
        const float* Wk_l = Wk + (size_t)l * DIM * DIM;
        const float* Wv_l = Wv + (size_t)l * DIM * DIM;
        const float* W1_l = W1 + (size_t)l * 4 * DIM * DIM;
        const float* W2_l = W2 + (size_t)l * 4 * DIM * DIM;

        gemm_bt<0,false><<<dim3(64, 8),  256, 0, stream>>>(x,  Wq_l, bq + l*DIM,   q, ROWS, DIM,  DIM, 1.f);
        gemm_bt<0,false><<<dim3(64, 8),  256, 0, stream>>>(cf, Wk_l, bk + l*DIM,   k, ROWS, DIM,  DIM, 1.f);
        gemm_bt<0,false><<<dim3(64, 8),  256, 0, stream>>>(cf, Wv_l, bv + l*DIM,   v, ROWS, DIM,  DIM, 1.f);
        gemm_bt<2,true ><<<dim3(64, 64), 256, 0, stream>>>(q,  k,    nullptr,      s, ROWS, ROWS, DIM, scale);
        softmax_rows<<<ROWS, 256, 0, stream>>>(s, ROWS);
        av_gemm<<<dim3(128, 8), 256, 0, stream>>>(s, v, t1);
        ln_res<<<ROWS / 4, 256, 0, stream>>>(x, t1, ln1g + l*DIM, ln1b + l*DIM);
        gemm_bt<1,false><<<dim3(64, 32), 256, 0, stream>>>(x, W1_l, b1 + l*4*DIM, h,  ROWS, 4*DIM, DIM,   1.f);
        gemm_bt<0,false><<<dim3(64, 8),  256, 0, stream>>>(h, W2_l, b2 + l*DIM,   t1, ROWS, DIM,   4*DIM, 1.f);
        ln_res<<<ROWS / 4, 256, 0, stream>>>(x, t1, ln2g + l*DIM, ln2b + l*DIM);
    }

    build_cat<<<4096, 256, 0, stream>>>((float4*)cat, (const float4*)cf, (const float4*)x);
    gemm_bt<0,false><<<dim3(64, 8), 256, 0, stream>>>(cat, Wsg, bsg, glog, ROWS, DIM, 2*DIM, 1.f);
    final_gate<<<2048, 256, 0, stream>>>((float4*)out, (const float4*)cf,
                                         (const float4*)x, (const float4*)glog);
}

// Round 2
// 528.232 us; speedup vs baseline: 3.2794x; 3.2794x over previous
//
#include <hip/hip_runtime.h>
#include <cmath>

// ---------------------------------------------------------------------------
// MemoryBankV2: B=128, T=32, D=512, L=2.  Rows = B*T = 4096.
// Round 2: bf16 MFMA GEMMs (m97 structure: 128x128 tile, BK=32,
// global_load_lds w=16, XOR-swizzled LDS, 16x16x32 bf16 MFMA).
// f32 residual stream; bf16 operand copies produced by epilogues.
// ---------------------------------------------------------------------------

#define ROWS 4096
#define DIM  512

typedef __bf16 bf16x8 __attribute__((ext_vector_type(8)));
typedef float  f32x4  __attribute__((ext_vector_type(4)));
typedef unsigned short u16;
typedef u16 u16x4 __attribute__((ext_vector_type(4)));
typedef u16 u16x8 __attribute__((ext_vector_type(8)));

__device__ __forceinline__ u16 f2bf(float x) {
    union { float f; unsigned u; } c; c.f = x;
    const unsigned r = (c.u + 0x7FFFu + ((c.u >> 16) & 1u)) >> 16;
    return (u16)r;
}
__device__ __forceinline__ float bf2f(u16 h) {
    union { unsigned u; float f; } c; c.u = ((unsigned)h) << 16;
    return c.f;
}

__device__ __forceinline__ void gload16(const void* g, void* l) {
    __builtin_amdgcn_global_load_lds(
        (const __attribute__((address_space(1))) void*)g,
        (__attribute__((address_space(3))) void*)l, 16, 0, 0);
}

// ---------------- MFMA GEMM body --------------------------------------------
// C[M,N] = epi(A[M,K] @ B[N,K]^T).  A,B bf16 (as u16), 128x128 tile, BK=32.
// LDS layout per tile: slot s(16B) = row*4 + (kg ^ ((row>>1)&3));
// staging: 4 consecutive lanes cover one row's 64B (kg permuted), so
// global_load_lds dest stays linear while ds_read_b128 is conflict-free.
// EPI: 0: f32 = acc*scale | 1: f32 = acc+bias | 2: bf16 = acc+bias
//      3: bf16 = gelu(acc+bias) | 4: bf16 transposed (C[col*ldc+row]) = acc+bias
// AVK: K-loop bound = m0+96 (block-causal attention AV gemm)
template<int EPI, bool AVK>
__device__ __forceinline__ void mgemm_body(
    const u16* __restrict__ A, int lda,
    const u16* __restrict__ B, int ldb,
    const float* __restrict__ bias,
    void* __restrict__ C, int ldc,
    int K, float scale, int m0, int n0, u16* smem)
{
    u16* As = smem;
    u16* Bs = smem + 4096;
    const int tid  = threadIdx.x;
    const int lane = tid & 63;
    const int w    = tid >> 6;          // wave 0..3
    const int wr   = (w >> 1) << 6;     // wave row base within tile
    const int wc   = (w & 1) << 6;      // wave col base within tile

    f32x4 acc[4][4];
    #pragma unroll
    for (int i = 0; i < 4; ++i)
        #pragma unroll
        for (int j = 0; j < 4; ++j)
            acc[i][j] = (f32x4){0.f, 0.f, 0.f, 0.f};

    // staging: wave w owns 16B-slots [w*128, w*128+128) of each tile (512 slots)
    const int sA0 = (w << 7) + lane, sA1 = sA0 + 64;
    const int r0 = sA0 >> 2, g0 = (sA0 & 3) ^ ((r0 >> 1) & 3);
    const int r1 = sA1 >> 2, g1 = (sA1 & 3) ^ ((r1 >> 1) & 3);
    const u16* pA0 = A + (size_t)(m0 + r0) * lda + (g0 << 3);
    const u16* pA1 = A + (size_t)(m0 + r1) * lda + (g1 << 3);
    const u16* pB0 = B + (size_t)(n0 + r0) * ldb + (g0 << 3);
    const u16* pB1 = B + (size_t)(n0 + r1) * ldb + (g1 << 3);
    u16* ldsA = As + (w << 10);         // chunk 2w base (u16 units)
    u16* ldsB = Bs + (w << 10);

    // fragment LDS offsets (k-step independent)
    const int l15 = lane & 15, kg = lane >> 4;
    int aoff[4], boff[4];
    #pragma unroll
    for (int i = 0; i < 4; ++i) {
        const int r = wr + (i << 4) + l15;
        aoff[i] = (((r << 2) + (kg ^ ((r >> 1) & 3))) << 3);
        const int c = wc + (i << 4) + l15;
        boff[i] = (((c << 2) + (kg ^ ((c >> 1) & 3))) << 3);
    }

    const int kEnd = AVK ? (m0 + 96) : K;

    for (int k0 = 0; k0 < kEnd; k0 += 32) {
        gload16(pA0 + k0, ldsA);
        gload16(pA1 + k0, ldsA + 512);
        gload16(pB0 + k0, ldsB);
        gload16(pB1 + k0, ldsB + 512);
        __syncthreads();                 // drains vmcnt before barrier
        bf16x8 af[4], bfr[4];
        #pragma unroll
        for (int i = 0; i < 4; ++i) af[i]  = *reinterpret_cast<const bf16x8*>(&As[aoff[i]]);
        #pragma unroll
        for (int j = 0; j < 4; ++j) bfr[j] = *reinterpret_cast<const bf16x8*>(&Bs[boff[j]]);
        #pragma unroll
        for (int i = 0; i < 4; ++i)
            #pragma unroll
            for (int j = 0; j < 4; ++j)
                acc[i][j] = __builtin_amdgcn_mfma_f32_16x16x32_bf16(af[i], bfr[j], acc[i][j], 0, 0, 0);
        __syncthreads();                 // protect LDS for next stage
    }

    // epilogue: C/D frag layout (m89-verified): col = lane&15, row = (lane>>4)*4 + reg
    const int lq = lane >> 4;
    #pragma unroll
    for (int j = 0; j < 4; ++j) {
        const int col = n0 + wc + (j << 4) + l15;
        const float bj = (EPI != 0) ? bias[col] : 0.f;
        #pragma unroll
        for (int i = 0; i < 4; ++i) {
            const int row0 = m0 + wr + (i << 4) + (lq << 2);
            if (EPI == 4) {
                u16x4 pk;
                #pragma unroll
                for (int r = 0; r < 4; ++r) pk[r] = f2bf(acc[i][j][r] + bj);
                *reinterpret_cast<u16x4*>(&((u16*)C)[(size_t)col * ldc + row0]) = pk;
            } else {
                #pragma unroll
                for (int r = 0; r < 4; ++r) {
                    float v = acc[i][j][r];
                    if (EPI == 0) v *= scale; else v += bj;
                    if (EPI == 3) v = 0.5f * v * (1.0f + erff(v * 0.70710678118654752f));
                    if (EPI == 0 || EPI == 1)
                        ((float*)C)[(size_t)(row0 + r) * ldc + col] = v;
                    else
                        ((u16*)C)[(size_t)(row0 + r) * ldc + col] = f2bf(v);
                }
            }
        }
    }
}

template<int EPI, bool SKIP, bool AVK>
__global__ __launch_bounds__(256) void mgemm(
    const u16* __restrict__ A, int lda, const u16* __restrict__ B, int ldb,
    const float* __restrict__ bias, void* __restrict__ C, int ldc, int K, float scale)
{
    const int m0 = blockIdx.x << 7;
    const int n0 = blockIdx.y << 7;
    if (SKIP && n0 > m0) return;        // block-causal: no valid cols past m0+95
    __shared__ u16 smem[8192];
    mgemm_body<EPI, AVK>(A, lda, B, ldb, bias, C, ldc, K, scale, m0, n0, smem);
}

// fused QKV: grid.y = which*4 + n_block.  q,k: bf16+bias; v: bf16+bias transposed
__global__ __launch_bounds__(256) void qkv_gemm(
    const u16* __restrict__ xa, const u16* __restrict__ cfb,
    const u16* __restrict__ Wqb, const u16* __restrict__ Wkb, const u16* __restrict__ Wvb,
    const float* __restrict__ bq, const float* __restrict__ bk, const float* __restrict__ bv,
    u16* __restrict__ q, u16* __restrict__ k, u16* __restrict__ vT)
{
    __shared__ u16 smem[8192];
    const int m0 = blockIdx.x << 7;
    const int which = blockIdx.y >> 2;
    const int n0 = (blockIdx.y & 3) << 7;
    if (which == 0)
        mgemm_body<2, false>(xa,  512, Wqb, 512, bq, q,  512,  512, 1.f, m0, n0, smem);
    else if (which == 1)
        mgemm_body<2, false>(cfb, 512, Wkb, 512, bk, k,  512,  512, 1.f, m0, n0, smem);
    else
        mgemm_body<4, false>(cfb, 512, Wvb, 512, bv, vT, 4096, 512, 1.f, m0, n0, smem);
}

// ---------------- masked row softmax: s(f32) -> p(bf16), zero ragged edge ---
__global__ __launch_bounds__(256) void softmax_pbf(
    const float* __restrict__ S, u16* __restrict__ P)
{
    const int row = blockIdx.x;
    const int b   = row >> 5;
    const int Lb  = b << 5;
    const int bound = ((row >> 7) << 7) + 96;   // AV gemm K bound for this block
    const float* s = S + (size_t)row * 4096;
    u16* p = P + (size_t)row * 4096;

    for (int m = Lb + threadIdx.x; m < bound; m += 256) p[m] = 0;
    if (b == 0) return;

    __shared__ float red[4];
    float mx = -3.0e38f;
    for (int m = threadIdx.x; m < Lb; m += 256) mx = fmaxf(mx, s[m]);
    #pragma unroll
    for (int off = 32; off; off >>= 1) mx = fmaxf(mx, __shfl_xor(mx, off));
    if ((threadIdx.x & 63) == 0) red[threadIdx.x >> 6] = mx;
    __syncthreads();
    mx = fmaxf(fmaxf(red[0], red[1]), fmaxf(red[2], red[3]));
    __syncthreads();

    float sum = 0.f;
    for (int m = threadIdx.x; m < Lb; m += 256) {
        const float e = expf(s[m] - mx);
        p[m] = f2bf(e);
        sum += e;
    }
    #pragma unroll
    for (int off = 32; off; off >>= 1) sum += __shfl_xor(sum, off);
    if ((threadIdx.x & 63) == 0) red[threadIdx.x >> 6] = sum;
    __syncthreads();
    sum = red[0] + red[1] + red[2] + red[3];
    const float inv = 1.0f / sum;
    for (int m = threadIdx.x; m < Lb; m += 256) p[m] = f2bf(bf2f(p[m]) * inv);
}

// ---------------- x = LN(xin + t); writes f32 x and bf16 copy ---------------
__global__ __launch_bounds__(256) void ln_res(
    const float* __restrict__ Xin, const float* __restrict__ T,
    const float* __restrict__ gamma, const float* __restrict__ beta,
    float* __restrict__ Xout, u16* __restrict__ Xbf)
{
    const int row  = blockIdx.x * 4 + (threadIdx.x >> 6);
    const int lane = threadIdx.x & 63;
    const float* xr = Xin + (size_t)row * DIM;
    const float* tr = T   + (size_t)row * DIM;
    const int d0 = lane << 3;

    const float4 x0 = *reinterpret_cast<const float4*>(&xr[d0]);
    const float4 x1 = *reinterpret_cast<const float4*>(&xr[d0 + 4]);
    const float4 t0 = *reinterpret_cast<const float4*>(&tr[d0]);
    const float4 t1 = *reinterpret_cast<const float4*>(&tr[d0 + 4]);
    float v[8] = {x0.x + t0.x, x0.y + t0.y, x0.z + t0.z, x0.w + t0.w,
                  x1.x + t1.x, x1.y + t1.y, x1.z + t1.z, x1.w + t1.w};

    float sm = 0.f;
    #pragma unroll
    for (int i = 0; i < 8; ++i) sm += v[i];
    #pragma unroll
    for (int off = 32; off; off >>= 1) sm += __shfl_xor(sm, off);
    const float mu = sm * (1.0f / 512.0f);

    float qs = 0.f;
    #pragma unroll
    for (int i = 0; i < 8; ++i) { const float d = v[i] - mu; qs += d * d; }
    #pragma unroll
    for (int off = 32; off; off >>= 1) qs += __shfl_xor(qs, off);
    const float rs = rsqrtf(qs * (1.0f / 512.0f) + 1e-5f);

    const float4 g0 = *reinterpret_cast<const float4*>(&gamma[d0]);
    const float4 g1 = *reinterpret_cast<const float4*>(&gamma[d0 + 4]);
    const float4 b0 = *reinterpret_cast<const float4*>(&beta[d0]);
    const float4 b1 = *reinterpret_cast<const float4*>(&beta[d0 + 4]);
    float o[8];
    o[0] = (v[0] - mu) * rs * g0.x + b0.x;
    o[1] = (v[1] - mu) * rs * g0.y + b0.y;
    o[2] = (v[2] - mu) * rs * g0.z + b0.z;
    o[3] = (v[3] - mu) * rs * g0.w + b0.w;
    o[4] = (v[4] - mu) * rs * g1.x + b1.x;
    o[5] = (v[5] - mu) * rs * g1.y + b1.y;
    o[6] = (v[6] - mu) * rs * g1.z + b1.z;
    o[7] = (v[7] - mu) * rs * g1.w + b1.w;

    float4 f0 = {o[0], o[1], o[2], o[3]}, f1 = {o[4], o[5], o[6], o[7]};
    *reinterpret_cast<float4*>(&Xout[(size_t)row * DIM + d0])     = f0;
    *reinterpret_cast<float4*>(&Xout[(size_t)row * DIM + d0 + 4]) = f1;
    u16x8 ob;
    #pragma unroll
    for (int i = 0; i < 8; ++i) ob[i] = f2bf(o[i]);
    *reinterpret_cast<u16x8*>(&Xbf[(size_t)row * DIM + d0]) = ob;
}

// ---------------- elementwise helpers ---------------------------------------
__global__ __launch_bounds__(256) void conv_bf(
    const float* __restrict__ s, u16* __restrict__ d)
{
    const int i = (blockIdx.x * 256 + threadIdx.x) << 3;
    const float4 a = *reinterpret_cast<const float4*>(&s[i]);
    const float4 b = *reinterpret_cast<const float4*>(&s[i + 4]);
    u16x8 o = {f2bf(a.x), f2bf(a.y), f2bf(a.z), f2bf(a.w),
               f2bf(b.x), f2bf(b.y), f2bf(b.z), f2bf(b.w)};
    *reinterpret_cast<u16x8*>(&d[i]) = o;
}

__global__ __launch_bounds__(256) void fix_x0(u16* __restrict__ xbf,
                                              const u16* __restrict__ cfb)
{
    const int i = (blockIdx.x * 256 + threadIdx.x) << 3;   // 16384 elems total
    *reinterpret_cast<u16x8*>(&xbf[i]) =
        *reinterpret_cast<const u16x8*>(&cfb[i]);
}

__global__ __launch_bounds__(256) void build_cat(
    u16* __restrict__ cat, const u16* __restrict__ cfb, const u16* __restrict__ xbf)
{
    const int idx = blockIdx.x * 256 + threadIdx.x;
    const int row = idx >> 7;
    const int c8  = idx & 127;
    const u16x8 v = (c8 < 64)
        ? *reinterpret_cast<const u16x8*>(&cfb[(size_t)row * 512 + (c8 << 3)])
        : *reinterpret_cast<const u16x8*>(&xbf[(size_t)row * 512 + ((c8 - 64) << 3)]);
    *reinterpret_cast<u16x8*>(&cat[(size_t)row * 1024 + (c8 << 3)]) = v;
}

__global__ __launch_bounds__(256) void final_gate(
    float4* __restrict__ out, const float4* __restrict__ cf,
    const float4* __restrict__ x, const float4* __restrict__ glog)
{
    const int idx = blockIdx.x * 256 + threadIdx.x;   // 524288 float4
    const int row = idx >> 7;
    const float4 zc = cf[idx];
    const float4 zg = glog[idx];
    const float4 za = (row < 32) ? zc : x[idx];
    float4 o;
    { const float g = 1.0f / (1.0f + expf(-zg.x)); o.x = g * zc.x + (1.0f - g) * za.x; }
    { const float g = 1.0f / (1.0f + expf(-zg.y)); o.y = g * zc.y + (1.0f - g) * za.y; }
    { const float g = 1.0f / (1.0f + expf(-zg.z)); o.z = g * zc.z + (1.0f - g) * za.z; }
    { const float g = 1.0f / (1.0f + expf(-zg.w)); o.w = g * zc.w + (1.0f - g) * za.w; }
    out[idx] = o;
}

// ---------------------------------------------------------------------------
extern "C" void kernel_launch(void* const* d_in, const int* in_sizes, int n_in,
                              void* d_out, int out_size, void* d_ws, size_t ws_size,
                              hipStream_t stream)
{
    const float* cf   = (const float*)d_in[0];
    const float* Wq   = (const float*)d_in[1];
    const float* bq   = (const float*)d_in[2];
    const float* Wk   = (const float*)d_in[3];
    const float* bk   = (const float*)d_in[4];
    const float* Wv   = (const float*)d_in[5];
    const float* bv   = (const float*)d_in[6];
    const float* ln1g = (const float*)d_in[7];
    const float* ln1b = (const float*)d_in[8];
    const float* W1   = (const float*)d_in[9];
    const float* b1   = (const float*)d_in[10];
    const float* W2   = (const float*)d_in[11];
    const float* b2   = (const float*)d_in[12];
    const float* ln2g = (const float*)d_in[13];
    const float* ln2b = (const float*)d_in[14];
    const float* Wsg  = (const float*)d_in[15];
    const float* bsg  = (const float*)d_in[16];
    float* out = (float*)d_out;

    const size_t RD = (size_t)ROWS * DIM;          // 2,097,152
    float* ws  = (float*)d_ws;
    float* x   = ws;                                // [4096,512] f32
    float* t1  = ws + RD;                           // [4096,512] f32 (also glog)
    float* s   = ws + 2 * RD;                       // [4096,4096] f32
    u16*  pbf  = (u16*)(ws + 10 * RD);              // shared: p / h / cat (bf16)
    u16*  hbf  = pbf;
    u16*  catb = pbf;
    u16*  bfb  = (u16*)(ws + 14 * RD);
    u16* cfb = bfb;                                 // [4096,512]
    u16* xbf = bfb + RD;
    u16* qbf = bfb + 2 * RD;
    u16* kbf = bfb + 3 * RD;
    u16* vTb = bfb + 4 * RD;                        // [512,4096] (V transposed)
    u16* Wqb = bfb + 5 * RD;
    u16* Wkb = Wqb + 524288;
    u16* Wvb = Wkb + 524288;
    u16* W1b = Wvb + 524288;
    u16* W2b = W1b + 2097152;
    u16* Wsb = W2b + 2097152;

    const float scale = 0.044194173824159216f;      // 1/sqrt(512)

    conv_bf<<<1024, 256, 0, stream>>>(cf, cfb);
    conv_bf<<<256,  256, 0, stream>>>(Wq, Wqb);
    conv_bf<<<256,  256, 0, stream>>>(Wk, Wkb);
    conv_bf<<<256,  256, 0, stream>>>(Wv, Wvb);
    conv_bf<<<1024, 256, 0, stream>>>(W1, W1b);
    conv_bf<<<1024, 256, 0, stream>>>(W2, W2b);
    conv_bf<<<256,  256, 0, stream>>>(Wsg, Wsb);

    for (int l = 0; l < 2; ++l) {
        const u16* xa = (l == 0) ? cfb : xbf;
        qkv_gemm<<<dim3(32, 12), 256, 0, stream>>>(
            xa, cfb, Wqb + l * 262144, Wkb + l * 262144, Wvb + l * 262144,
            bq + l * 512, bk + l * 512, bv + l * 512, qbf, kbf, vTb);
        mgemm<0, true, false><<<dim3(32, 32), 256, 0, stream>>>(
            qbf, 512, kbf, 512, nullptr, s, 4096, 512, scale);
        softmax_pbf<<<4096, 256, 0, stream>>>(s, pbf);
        mgemm<0, false, true><<<dim3(32, 4), 256, 0, stream>>>(
            pbf, 4096, vTb, 4096, nullptr, t1, 512, 4096, 1.f);
        ln_res<<<1024, 256, 0, stream>>>(
            (l == 0) ? cf : x, t1, ln1g + l * 512, ln1b + l * 512, x, xbf);
        mgemm<3, false, false><<<dim3(32, 16), 256, 0, stream>>>(
            xbf, 512, W1b + l * 1048576, 512, b1 + l * 2048, hbf, 2048, 512, 1.f);
        mgemm<1, false, false><<<dim3(32, 4), 256, 0, stream>>>(
            hbf, 2048, W2b + l * 1048576, 2048, b2 + l * 512, t1, 512, 2048, 1.f);
        ln_res<<<1024, 256, 0, stream>>>(
            x, t1, ln2g + l * 512, ln2b + l * 512, x, xbf);
    }

    fix_x0<<<8, 256, 0, stream>>>(xbf, cfb);              // attn_out rows 0..31 = cf
    build_cat<<<2048, 256, 0, stream>>>(catb, cfb, xbf);
    mgemm<1, false, false><<<dim3(32, 4), 256, 0, stream>>>(
        catb, 1024, Wsb, 1024, bsg, t1, 512, 1024, 1.f);
    final_gate<<<2048, 256, 0, stream>>>((float4*)out, (const float4*)cf,
                                         (const float4*)x, (const float4*)t1);
}

// Round 3
// 326.787 us; speedup vs baseline: 5.3010x; 1.6164x over previous
//
#include <hip/hip_runtime.h>
#include <cmath>

// ---------------------------------------------------------------------------
// MemoryBankV2: B=128, T=32, D=512, L=2.  Rows = B*T = 4096.
// Round 3: + double-buffered 2-phase MFMA pipeline (1 barrier/K-step),
//          + split-K partials for the skinny N=512 GEMMs (AV, MLP2, gate),
//            fused reduction into ln_res / final_gate consumers.
// ---------------------------------------------------------------------------

#define ROWS 4096
#define DIM  512

typedef __bf16 bf16x8 __attribute__((ext_vector_type(8)));
typedef float  f32x4  __attribute__((ext_vector_type(4)));
typedef unsigned short u16;
typedef u16 u16x4 __attribute__((ext_vector_type(4)));
typedef u16 u16x8 __attribute__((ext_vector_type(8)));

#define RD ((size_t)ROWS * DIM)

__device__ __forceinline__ u16 f2bf(float x) {
    union { float f; unsigned u; } c; c.f = x;
    const unsigned r = (c.u + 0x7FFFu + ((c.u >> 16) & 1u)) >> 16;
    return (u16)r;
}
__device__ __forceinline__ float bf2f(u16 h) {
    union { unsigned u; float f; } c; c.u = ((unsigned)h) << 16;
    return c.f;
}

__device__ __forceinline__ void gload16(const void* g, void* l) {
    __builtin_amdgcn_global_load_lds(
        (const __attribute__((address_space(1))) void*)g,
        (__attribute__((address_space(3))) void*)l, 16, 0, 0);
}

// ---------------- MFMA GEMM body --------------------------------------------
// C[M,N](+=) epi(A[M,K] @ B[N,K]^T), K range [kBeg,kEnd), 128x128 tile, BK=32.
// LDS: slot s(16B) = row*4 + (kg ^ ((row>>1)&3)) per tile; double buffered.
// EPI: 0: f32 = acc*scale | 1: f32 = acc+bias | 2: bf16 = acc+bias
//      3: bf16 = gelu(acc+bias) | 4: bf16 transposed (C[col*ldc+row]) = acc+bias
template<int EPI>
__device__ __forceinline__ void mgemm_body(
    const u16* __restrict__ A, int lda,
    const u16* __restrict__ B, int ldb,
    const float* __restrict__ bias,
    void* __restrict__ C, int ldc,
    int kBeg, int kEnd, float scale, int m0, int n0, u16* smem)
{
    const int tid  = threadIdx.x;
    const int lane = tid & 63;
    const int w    = tid >> 6;          // wave 0..3
    const int wr   = (w >> 1) << 6;     // wave row base within tile
    const int wc   = (w & 1) << 6;      // wave col base within tile

    f32x4 acc[4][4];
    #pragma unroll
    for (int i = 0; i < 4; ++i)
        #pragma unroll
        for (int j = 0; j < 4; ++j)
            acc[i][j] = (f32x4){0.f, 0.f, 0.f, 0.f};

    // staging: wave w owns 16B-slots [w*128, w*128+128) of each tile
    const int sA0 = (w << 7) + lane, sA1 = sA0 + 64;
    const int r0 = sA0 >> 2, g0 = (sA0 & 3) ^ ((r0 >> 1) & 3);
    const int r1 = sA1 >> 2, g1 = (sA1 & 3) ^ ((r1 >> 1) & 3);
    const u16* pA0 = A + (size_t)(m0 + r0) * lda + (g0 << 3) + kBeg;
    const u16* pA1 = A + (size_t)(m0 + r1) * lda + (g1 << 3) + kBeg;
    const u16* pB0 = B + (size_t)(n0 + r0) * ldb + (g0 << 3) + kBeg;
    const u16* pB1 = B + (size_t)(n0 + r1) * ldb + (g1 << 3) + kBeg;
    const int wofs = w << 10;           // wave's 2KB chunk within a tile (u16)

    // fragment LDS offsets (within-buffer, k-step independent)
    const int l15 = lane & 15, kg = lane >> 4;
    int aoff[4], boff[4];
    #pragma unroll
    for (int i = 0; i < 4; ++i) {
        const int r = wr + (i << 4) + l15;
        aoff[i] = (((r << 2) + (kg ^ ((r >> 1) & 3))) << 3);
        const int c = wc + (i << 4) + l15;
        boff[i] = 4096 + (((c << 2) + (kg ^ ((c >> 1) & 3))) << 3);
    }

    const int nt = (kEnd - kBeg) >> 5;

    if (nt > 0) {
        // prologue: stage tile 0 into buf 0
        {
            u16* la = smem + wofs;
            u16* lb = la + 4096;
            gload16(pA0, la); gload16(pA1, la + 512);
            gload16(pB0, lb); gload16(pB1, lb + 512);
        }
        __syncthreads();
        for (int t = 0; t < nt; ++t) {
            const int cur = t & 1;
            if (t + 1 < nt) {            // issue next-tile loads early
                const int ko = (t + 1) << 5;
                u16* la = smem + ((cur ^ 1) << 13) + wofs;
                u16* lb = la + 4096;
                gload16(pA0 + ko, la); gload16(pA1 + ko, la + 512);
                gload16(pB0 + ko, lb); gload16(pB1 + ko, lb + 512);
            }
            const u16* buf = smem + (cur << 13);
            bf16x8 af[4], bfr[4];
            #pragma unroll
            for (int i = 0; i < 4; ++i) af[i]  = *reinterpret_cast<const bf16x8*>(&buf[aoff[i]]);
            #pragma unroll
            for (int j = 0; j < 4; ++j) bfr[j] = *reinterpret_cast<const bf16x8*>(&buf[boff[j]]);
            #pragma unroll
            for (int i = 0; i < 4; ++i)
                #pragma unroll
                for (int j = 0; j < 4; ++j)
                    acc[i][j] = __builtin_amdgcn_mfma_f32_16x16x32_bf16(af[i], bfr[j], acc[i][j], 0, 0, 0);
            __syncthreads();             // drains vmcnt (next buf ready) + LDS reuse
        }
    }

    // epilogue: C/D frag layout: col = lane&15, row = (lane>>4)*4 + reg
    const int lq = lane >> 4;
    #pragma unroll
    for (int j = 0; j < 4; ++j) {
        const int col = n0 + wc + (j << 4) + l15;
        const float bj = (EPI != 0) ? bias[col] : 0.f;
        #pragma unroll
        for (int i = 0; i < 4; ++i) {
            const int row0 = m0 + wr + (i << 4) + (lq << 2);
            if (EPI == 4) {
                u16x4 pk;
                #pragma unroll
                for (int r = 0; r < 4; ++r) pk[r] = f2bf(acc[i][j][r] + bj);
                *reinterpret_cast<u16x4*>(&((u16*)C)[(size_t)col * ldc + row0]) = pk;
            } else {
                #pragma unroll
                for (int r = 0; r < 4; ++r) {
                    float v = acc[i][j][r];
                    if (EPI == 0) v *= scale; else v += bj;
                    if (EPI == 3) v = 0.5f * v * (1.0f + erff(v * 0.70710678118654752f));
                    if (EPI == 0 || EPI == 1)
                        ((float*)C)[(size_t)(row0 + r) * ldc + col] = v;
                    else
                        ((u16*)C)[(size_t)(row0 + r) * ldc + col] = f2bf(v);
                }
            }
        }
    }
}

template<int EPI, bool SKIP>
__global__ __launch_bounds__(256) void mgemm(
    const u16* __restrict__ A, int lda, const u16* __restrict__ B, int ldb,
    const float* __restrict__ bias, void* __restrict__ C, int ldc, int K, float scale)
{
    const int m0 = blockIdx.x << 7;
    const int n0 = blockIdx.y << 7;
    if (SKIP && n0 > m0) return;        // block-causal: no valid cols past m0+95
    __shared__ u16 smem[16384];
    mgemm_body<EPI>(A, lda, B, ldb, bias, C, ldc, 0, K, scale, m0, n0, smem);
}

// split-K partial GEMM: writes raw f32 acc to Cpart + z*RD.  AVK: Klim = m0+96.
template<bool AVK>
__global__ __launch_bounds__(256) void mgemm_pk(
    const u16* __restrict__ A, int lda, const u16* __restrict__ B, int ldb,
    float* __restrict__ Cpart, int K, int chunk)
{
    const int m0 = blockIdx.x << 7;
    const int n0 = blockIdx.y << 7;
    const int z  = blockIdx.z;
    const int Klim = AVK ? (m0 + 96) : K;
    int kBeg = z * chunk; if (kBeg > Klim) kBeg = Klim;
    int kEnd = kBeg + chunk; if (kEnd > Klim) kEnd = Klim;
    __shared__ u16 smem[16384];
    mgemm_body<0>(A, lda, B, ldb, nullptr, Cpart + (size_t)z * RD, 512,
                  kBeg, kEnd, 1.f, m0, n0, smem);
}

// fused QKV: grid.y = which*4 + n_block.  q,k: bf16+bias; v: bf16+bias transposed
__global__ __launch_bounds__(256) void qkv_gemm(
    const u16* __restrict__ xa, const u16* __restrict__ cfb,
    const u16* __restrict__ Wqb, const u16* __restrict__ Wkb, const u16* __restrict__ Wvb,
    const float* __restrict__ bq, const float* __restrict__ bk, const float* __restrict__ bv,
    u16* __restrict__ q, u16* __restrict__ k, u16* __restrict__ vT)
{
    __shared__ u16 smem[16384];
    const int m0 = blockIdx.x << 7;
    const int which = blockIdx.y >> 2;
    const int n0 = (blockIdx.y & 3) << 7;
    if (which == 0)
        mgemm_body<2>(xa,  512, Wqb, 512, bq, q,  512,  0, 512, 1.f, m0, n0, smem);
    else if (which == 1)
        mgemm_body<2>(cfb, 512, Wkb, 512, bk, k,  512,  0, 512, 1.f, m0, n0, smem);
    else
        mgemm_body<4>(cfb, 512, Wvb, 512, bv, vT, 4096, 0, 512, 1.f, m0, n0, smem);
}

// ---------------- masked row softmax: s(f32) -> p(bf16), zero ragged edge ---
__global__ __launch_bounds__(256) void softmax_pbf(
    const float* __restrict__ S, u16* __restrict__ P)
{
    const int row = blockIdx.x;
    const int b   = row >> 5;
    const int Lb  = b << 5;
    const int bound = ((row >> 7) << 7) + 96;   // AV gemm K bound for this block
    const float* s = S + (size_t)row * 4096;
    u16* p = P + (size_t)row * 4096;

    for (int m = Lb + threadIdx.x; m < bound; m += 256) p[m] = 0;
    if (b == 0) return;

    __shared__ float red[4];
    float mx = -3.0e38f;
    for (int m = threadIdx.x; m < Lb; m += 256) mx = fmaxf(mx, s[m]);
    #pragma unroll
    for (int off = 32; off; off >>= 1) mx = fmaxf(mx, __shfl_xor(mx, off));
    if ((threadIdx.x & 63) == 0) red[threadIdx.x >> 6] = mx;
    __syncthreads();
    mx = fmaxf(fmaxf(red[0], red[1]), fmaxf(red[2], red[3]));
    __syncthreads();

    float sum = 0.f;
    for (int m = threadIdx.x; m < Lb; m += 256) {
        const float e = expf(s[m] - mx);
        p[m] = f2bf(e);
        sum += e;
    }
    #pragma unroll
    for (int off = 32; off; off >>= 1) sum += __shfl_xor(sum, off);
    if ((threadIdx.x & 63) == 0) red[threadIdx.x >> 6] = sum;
    __syncthreads();
    sum = red[0] + red[1] + red[2] + red[3];
    const float inv = 1.0f / sum;
    for (int m = threadIdx.x; m < Lb; m += 256) p[m] = f2bf(bf2f(p[m]) * inv);
}

// ------- x = LN(xin + sum_s part[s] (+bias)); writes f32 x and bf16 copy ----
template<int NS, bool HASB>
__global__ __launch_bounds__(256) void ln_res_ps(
    const float* __restrict__ Xin, const float* __restrict__ part,
    const float* __restrict__ bias,
    const float* __restrict__ gamma, const float* __restrict__ beta,
    float* __restrict__ Xout, u16* __restrict__ Xbf)
{
    const int row  = blockIdx.x * 4 + (threadIdx.x >> 6);
    const int lane = threadIdx.x & 63;
    const float* xr = Xin + (size_t)row * DIM;
    const int d0 = lane << 3;

    const float4 x0 = *reinterpret_cast<const float4*>(&xr[d0]);
    const float4 x1 = *reinterpret_cast<const float4*>(&xr[d0 + 4]);
    float v[8] = {x0.x, x0.y, x0.z, x0.w, x1.x, x1.y, x1.z, x1.w};
    #pragma unroll
    for (int s = 0; s < NS; ++s) {
        const float* pr = part + (size_t)s * RD + (size_t)row * DIM + d0;
        const float4 p0 = *reinterpret_cast<const float4*>(pr);
        const float4 p1 = *reinterpret_cast<const float4*>(pr + 4);
        v[0] += p0.x; v[1] += p0.y; v[2] += p0.z; v[3] += p0.w;
        v[4] += p1.x; v[5] += p1.y; v[6] += p1.z; v[7] += p1.w;
    }
    if (HASB) {
        const float4 b0 = *reinterpret_cast<const float4*>(&bias[d0]);
        const float4 b1 = *reinterpret_cast<const float4*>(&bias[d0 + 4]);
        v[0] += b0.x; v[1] += b0.y; v[2] += b0.z; v[3] += b0.w;
        v[4] += b1.x; v[5] += b1.y; v[6] += b1.z; v[7] += b1.w;
    }

    float sm = 0.f;
    #pragma unroll
    for (int i = 0; i < 8; ++i) sm += v[i];
    #pragma unroll
    for (int off = 32; off; off >>= 1) sm += __shfl_xor(sm, off);
    const float mu = sm * (1.0f / 512.0f);

    float qs = 0.f;
    #pragma unroll
    for (int i = 0; i < 8; ++i) { const float d = v[i] - mu; qs += d * d; }
    #pragma unroll
    for (int off = 32; off; off >>= 1) qs += __shfl_xor(qs, off);
    const float rs = rsqrtf(qs * (1.0f / 512.0f) + 1e-5f);

    const float4 g0 = *reinterpret_cast<const float4*>(&gamma[d0]);
    const float4 g1 = *reinterpret_cast<const float4*>(&gamma[d0 + 4]);
    const float4 b0 = *reinterpret_cast<const float4*>(&beta[d0]);
    const float4 b1 = *reinterpret_cast<const float4*>(&beta[d0 + 4]);
    float o[8];
    o[0] = (v[0] - mu) * rs * g0.x + b0.x;
    o[1] = (v[1] - mu) * rs * g0.y + b0.y;
    o[2] = (v[2] - mu) * rs * g0.z + b0.z;
    o[3] = (v[3] - mu) * rs * g0.w + b0.w;
    o[4] = (v[4] - mu) * rs * g1.x + b1.x;
    o[5] = (v[5] - mu) * rs * g1.y + b1.y;
    o[6] = (v[6] - mu) * rs * g1.z + b1.z;
    o[7] = (v[7] - mu) * rs * g1.w + b1.w;

    float4 f0 = {o[0], o[1], o[2], o[3]}, f1 = {o[4], o[5], o[6], o[7]};
    *reinterpret_cast<float4*>(&Xout[(size_t)row * DIM + d0])     = f0;
    *reinterpret_cast<float4*>(&Xout[(size_t)row * DIM + d0 + 4]) = f1;
    u16x8 ob;
    #pragma unroll
    for (int i = 0; i < 8; ++i) ob[i] = f2bf(o[i]);
    *reinterpret_cast<u16x8*>(&Xbf[(size_t)row * DIM + d0]) = ob;
}

// ---------------- elementwise helpers ---------------------------------------
__global__ __launch_bounds__(256) void conv_bf(
    const float* __restrict__ s, u16* __restrict__ d)
{
    const int i = (blockIdx.x * 256 + threadIdx.x) << 3;
    const float4 a = *reinterpret_cast<const float4*>(&s[i]);
    const float4 b = *reinterpret_cast<const float4*>(&s[i + 4]);
    u16x8 o = {f2bf(a.x), f2bf(a.y), f2bf(a.z), f2bf(a.w),
               f2bf(b.x), f2bf(b.y), f2bf(b.z), f2bf(b.w)};
    *reinterpret_cast<u16x8*>(&d[i]) = o;
}

__global__ __launch_bounds__(256) void fix_x0(u16* __restrict__ xbf,
                                              const u16* __restrict__ cfb)
{
    const int i = (blockIdx.x * 256 + threadIdx.x) << 3;   // 16384 elems total
    *reinterpret_cast<u16x8*>(&xbf[i]) =
        *reinterpret_cast<const u16x8*>(&cfb[i]);
}

__global__ __launch_bounds__(256) void build_cat(
    u16* __restrict__ cat, const u16* __restrict__ cfb, const u16* __restrict__ xbf)
{
    const int idx = blockIdx.x * 256 + threadIdx.x;
    const int row = idx >> 7;
    const int c8  = idx & 127;
    const u16x8 v = (c8 < 64)
        ? *reinterpret_cast<const u16x8*>(&cfb[(size_t)row * 512 + (c8 << 3)])
        : *reinterpret_cast<const u16x8*>(&xbf[(size_t)row * 512 + ((c8 - 64) << 3)]);
    *reinterpret_cast<u16x8*>(&cat[(size_t)row * 1024 + (c8 << 3)]) = v;
}

// out = g*cf + (1-g)*attn, g = sigmoid(part0+part1+bias), attn = (row<32? cf : x)
__global__ __launch_bounds__(256) void final_gate_ps(
    float4* __restrict__ out, const float4* __restrict__ cf,
    const float4* __restrict__ x, const float* __restrict__ part,
    const float* __restrict__ bias)
{
    const int idx = blockIdx.x * 256 + threadIdx.x;   // 524288 float4
    const int row = idx >> 7;
    const int c4  = idx & 127;
    const float4 zc = cf[idx];
    const float4 p0 = reinterpret_cast<const float4*>(part)[idx];
    const float4 p1 = reinterpret_cast<const float4*>(part + RD)[idx];
    const float4 bb = *reinterpret_cast<const float4*>(&bias[c4 << 2]);
    const float4 za = (row < 32) ? zc : x[idx];
    float4 o;
    { const float g = 1.0f / (1.0f + expf(-(p0.x + p1.x + bb.x))); o.x = g * zc.x + (1.0f - g) * za.x; }
    { const float g = 1.0f / (1.0f + expf(-(p0.y + p1.y + bb.y))); o.y = g * zc.y + (1.0f - g) * za.y; }
    { const float g = 1.0f / (1.0f + expf(-(p0.z + p1.z + bb.z))); o.z = g * zc.z + (1.0f - g) * za.z; }
    { const float g = 1.0f / (1.0f + expf(-(p0.w + p1.w + bb.w))); o.w = g * zc.w + (1.0f - g) * za.w; }
    out[idx] = o;
}

// ---------------------------------------------------------------------------
extern "C" void kernel_launch(void* const* d_in, const int* in_sizes, int n_in,
                              void* d_out, int out_size, void* d_ws, size_t ws_size,
                              hipStream_t stream)
{
    const float* cf   = (const float*)d_in[0];
    const float* Wq   = (const float*)d_in[1];
    const float* bq   = (const float*)d_in[2];
    const float* Wk   = (const float*)d_in[3];
    const float* bk   = (const float*)d_in[4];
    const float* Wv   = (const float*)d_in[5];
    const float* bv   = (const float*)d_in[6];
    const float* ln1g = (const float*)d_in[7];
    const float* ln1b = (const float*)d_in[8];
    const float* W1   = (const float*)d_in[9];
    const float* b1   = (const float*)d_in[10];
    const float* W2   = (const float*)d_in[11];
    const float* b2   = (const float*)d_in[12];
    const float* ln2g = (const float*)d_in[13];
    const float* ln2b = (const float*)d_in[14];
    const float* Wsg  = (const float*)d_in[15];
    const float* bsg  = (const float*)d_in[16];
    float* out = (float*)d_out;

    float* ws  = (float*)d_ws;
    float* x   = ws;                                // [4096,512] f32
    float* s   = ws + 2 * RD;                       // [4096,4096] f32 (attn phase)
    float* part= ws + 2 * RD;                       // 4x[4096,512] f32 partials
                                                    // (aliases s; s is dead then)
    u16*  pbf  = (u16*)(ws + 10 * RD);              // shared: p / h / cat (bf16)
    u16*  hbf  = pbf;
    u16*  catb = pbf;
    u16*  bfb  = (u16*)(ws + 14 * RD);
    u16* cfb = bfb;                                 // [4096,512]
    u16* xbf = bfb + RD;
    u16* qbf = bfb + 2 * RD;
    u16* kbf = bfb + 3 * RD;
    u16* vTb = bfb + 4 * RD;                        // [512,4096] (V transposed)
    u16* Wqb = bfb + 5 * RD;
    u16* Wkb = Wqb + 524288;
    u16* Wvb = Wkb + 524288;
    u16* W1b = Wvb + 524288;
    u16* W2b = W1b + 2097152;
    u16* Wsb = W2b + 2097152;

    const float scale = 0.044194173824159216f;      // 1/sqrt(512)

    conv_bf<<<1024, 256, 0, stream>>>(cf, cfb);
    conv_bf<<<256,  256, 0, stream>>>(Wq, Wqb);
    conv_bf<<<256,  256, 0, stream>>>(Wk, Wkb);
    conv_bf<<<256,  256, 0, stream>>>(Wv, Wvb);
    conv_bf<<<1024, 256, 0, stream>>>(W1, W1b);
    conv_bf<<<1024, 256, 0, stream>>>(W2, W2b);
    conv_bf<<<256,  256, 0, stream>>>(Wsg, Wsb);

    for (int l = 0; l < 2; ++l) {
        const u16* xa = (l == 0) ? cfb : xbf;
        qkv_gemm<<<dim3(32, 12), 256, 0, stream>>>(
            xa, cfb, Wqb + l * 262144, Wkb + l * 262144, Wvb + l * 262144,
            bq + l * 512, bk + l * 512, bv + l * 512, qbf, kbf, vTb);
        mgemm<0, true><<<dim3(32, 32), 256, 0, stream>>>(
            qbf, 512, kbf, 512, nullptr, s, 4096, 512, scale);
        softmax_pbf<<<4096, 256, 0, stream>>>(s, pbf);
        // AV: split-K 4 x 1024 (s region is dead now -> partials alias it)
        mgemm_pk<true><<<dim3(32, 4, 4), 256, 0, stream>>>(
            pbf, 4096, vTb, 4096, part, 4096, 1024);
        ln_res_ps<4, false><<<1024, 256, 0, stream>>>(
            (l == 0) ? cf : x, part, nullptr, ln1g + l * 512, ln1b + l * 512, x, xbf);
        mgemm<3, false><<<dim3(32, 16), 256, 0, stream>>>(
            xbf, 512, W1b + l * 1048576, 512, b1 + l * 2048, hbf, 2048, 512, 1.f);
        // MLP2: split-K 4 x 512
        mgemm_pk<false><<<dim3(32, 4, 4), 256, 0, stream>>>(
            hbf, 2048, W2b + l * 1048576, 2048, part, 2048, 512);
        ln_res_ps<4, true><<<1024, 256, 0, stream>>>(
            x, part, b2 + l * 512, ln2g + l * 512, ln2b + l * 512, x, xbf);
    }

    fix_x0<<<8, 256, 0, stream>>>(xbf, cfb);              // attn_out rows 0..31 = cf
    build_cat<<<2048, 256, 0, stream>>>(catb, cfb, xbf);
    // gate: split-K 2 x 512
    mgemm_pk<false><<<dim3(32, 4, 2), 256, 0, stream>>>(
        catb, 1024, Wsb, 1024, part, 1024, 512);
    final_gate_ps<<<2048, 256, 0, stream>>>((float4*)out, (const float4*)cf,
                                            (const float4*)x, part, bsg);
}

// Round 4
// 318.896 us; speedup vs baseline: 5.4322x; 1.0247x over previous
//
#include <hip/hip_runtime.h>
#include <cmath>

// ---------------------------------------------------------------------------
// MemoryBankV2: B=128, T=32, D=512, L=2.  Rows = B*T = 4096.
// Round 4: depth-2 software pipeline with counted vmcnt (loads stay in flight
// across barriers), triple-buffered LDS, setprio around MFMA, triangular
// grid for the block-causal score GEMM, balanced AV split-K, fused convs.
// ---------------------------------------------------------------------------

#define ROWS 4096
#define DIM  512

typedef __bf16 bf16x8 __attribute__((ext_vector_type(8)));
typedef float  f32x4  __attribute__((ext_vector_type(4)));
typedef unsigned short u16;
typedef u16 u16x4 __attribute__((ext_vector_type(4)));
typedef u16 u16x8 __attribute__((ext_vector_type(8)));

#define RD ((size_t)ROWS * DIM)

__device__ __forceinline__ u16 f2bf(float x) {
    union { float f; unsigned u; } c; c.f = x;
    const unsigned r = (c.u + 0x7FFFu + ((c.u >> 16) & 1u)) >> 16;
    return (u16)r;
}
__device__ __forceinline__ float bf2f(u16 h) {
    union { unsigned u; float f; } c; c.u = ((unsigned)h) << 16;
    return c.f;
}

__device__ __forceinline__ void gload16(const void* g, void* l) {
    __builtin_amdgcn_global_load_lds(
        (const __attribute__((address_space(1))) void*)g,
        (__attribute__((address_space(3))) void*)l, 16, 0, 0);
}

// ---------------- MFMA GEMM body --------------------------------------------
// C[M,N] = epi(A[M,K] @ B[N,K]^T), K range [kBeg,kEnd), 128x128 tile, BK=32.
// LDS: slot s(16B) = row*4 + (kg ^ ((row>>1)&3)); TRIPLE buffered (48KB),
// depth-2 prefetch with counted vmcnt(4) so one tile's loads stay in flight
// across the barrier.
// EPI: 0: f32 = acc*scale | 1: f32 = acc+bias | 2: bf16 = acc+bias
//      3: bf16 = gelu(acc+bias) | 4: bf16 transposed (C[col*ldc+row]) = acc+bias
template<int EPI>
__device__ __forceinline__ void mgemm_body(
    const u16* __restrict__ A, int lda,
    const u16* __restrict__ B, int ldb,
    const float* __restrict__ bias,
    void* __restrict__ C, int ldc,
    int kBeg, int kEnd, float scale, int m0, int n0, u16* smem)
{
    const int tid  = threadIdx.x;
    const int lane = tid & 63;
    const int w    = tid >> 6;          // wave 0..3
    const int wr   = (w >> 1) << 6;     // wave row base within tile
    const int wc   = (w & 1) << 6;      // wave col base within tile

    f32x4 acc[4][4];
    #pragma unroll
    for (int i = 0; i < 4; ++i)
        #pragma unroll
        for (int j = 0; j < 4; ++j)
            acc[i][j] = (f32x4){0.f, 0.f, 0.f, 0.f};

    // staging: wave w owns 16B-slots [w*128, w*128+128) of each half-tile
    const int sA0 = (w << 7) + lane, sA1 = sA0 + 64;
    const int r0 = sA0 >> 2, g0 = (sA0 & 3) ^ ((r0 >> 1) & 3);
    const int r1 = sA1 >> 2, g1 = (sA1 & 3) ^ ((r1 >> 1) & 3);
    const u16* pA0 = A + (size_t)(m0 + r0) * lda + (g0 << 3) + kBeg;
    const u16* pA1 = A + (size_t)(m0 + r1) * lda + (g1 << 3) + kBeg;
    const u16* pB0 = B + (size_t)(n0 + r0) * ldb + (g0 << 3) + kBeg;
    const u16* pB1 = B + (size_t)(n0 + r1) * ldb + (g1 << 3) + kBeg;
    const int wofs = w << 10;           // wave's 2KB chunk within a tile (u16)

    // fragment LDS offsets (within-buffer, k-step independent)
    const int l15 = lane & 15, kg = lane >> 4;
    int aoff[4], boff[4];
    #pragma unroll
    for (int i = 0; i < 4; ++i) {
        const int r = wr + (i << 4) + l15;
        aoff[i] = (((r << 2) + (kg ^ ((r >> 1) & 3))) << 3);
        const int c = wc + (i << 4) + l15;
        boff[i] = 4096 + (((c << 2) + (kg ^ ((c >> 1) & 3))) << 3);
    }

    const int nt = (kEnd - kBeg) >> 5;

    if (nt > 0) {
        // prologue: stage tiles 0 (buf0) and 1 (buf1)
        {
            u16* la = smem + wofs; u16* lb = la + 4096;
            gload16(pA0, la); gload16(pA1, la + 512);
            gload16(pB0, lb); gload16(pB1, lb + 512);
        }
        if (nt > 1) {
            u16* la = smem + 8192 + wofs; u16* lb = la + 4096;
            gload16(pA0 + 32, la); gload16(pA1 + 32, la + 512);
            gload16(pB0 + 32, lb); gload16(pB1 + 32, lb + 512);
        }
        int bread = 0;                  // buffer holding tile t
        for (int t = 0; t < nt; ++t) {
            // wait for tile t's loads (leave tile t+1's 4 in flight)
            if (t == nt - 1) asm volatile("s_waitcnt vmcnt(0)" ::: "memory");
            else             asm volatile("s_waitcnt vmcnt(4)" ::: "memory");
            __builtin_amdgcn_s_barrier();
            asm volatile("" ::: "memory");   // pin ds_reads below barrier

            const u16* buf = smem + (bread << 13);
            bf16x8 af[4], bfr[4];
            #pragma unroll
            for (int i = 0; i < 4; ++i) af[i]  = *reinterpret_cast<const bf16x8*>(&buf[aoff[i]]);
            #pragma unroll
            for (int j = 0; j < 4; ++j) bfr[j] = *reinterpret_cast<const bf16x8*>(&buf[boff[j]]);

            if (t + 2 < nt) {            // stage tile t+2 into buf (bread+2)%3
                const int bst = (bread == 0) ? 2 : bread - 1;
                const int ko = (t + 2) << 5;
                u16* la = smem + (bst << 13) + wofs; u16* lb = la + 4096;
                gload16(pA0 + ko, la); gload16(pA1 + ko, la + 512);
                gload16(pB0 + ko, lb); gload16(pB1 + ko, lb + 512);
            }

            __builtin_amdgcn_s_setprio(1);
            #pragma unroll
            for (int i = 0; i < 4; ++i)
                #pragma unroll
                for (int j = 0; j < 4; ++j)
                    acc[i][j] = __builtin_amdgcn_mfma_f32_16x16x32_bf16(af[i], bfr[j], acc[i][j], 0, 0, 0);
            __builtin_amdgcn_s_setprio(0);

            bread = (bread == 2) ? 0 : bread + 1;
        }
    }

    // epilogue: C/D frag layout: col = lane&15, row = (lane>>4)*4 + reg
    const int lq = lane >> 4;
    #pragma unroll
    for (int j = 0; j < 4; ++j) {
        const int col = n0 + wc + (j << 4) + l15;
        const float bj = (EPI != 0) ? bias[col] : 0.f;
        #pragma unroll
        for (int i = 0; i < 4; ++i) {
            const int row0 = m0 + wr + (i << 4) + (lq << 2);
            if (EPI == 4) {
                u16x4 pk;
                #pragma unroll
                for (int r = 0; r < 4; ++r) pk[r] = f2bf(acc[i][j][r] + bj);
                *reinterpret_cast<u16x4*>(&((u16*)C)[(size_t)col * ldc + row0]) = pk;
            } else {
                #pragma unroll
                for (int r = 0; r < 4; ++r) {
                    float v = acc[i][j][r];
                    if (EPI == 0) v *= scale; else v += bj;
                    if (EPI == 3) v = 0.5f * v * (1.0f + erff(v * 0.70710678118654752f));
                    if (EPI == 0 || EPI == 1)
                        ((float*)C)[(size_t)(row0 + r) * ldc + col] = v;
                    else
                        ((u16*)C)[(size_t)(row0 + r) * ldc + col] = f2bf(v);
                }
            }
        }
    }
}

template<int EPI>
__global__ __launch_bounds__(256) void mgemm(
    const u16* __restrict__ A, int lda, const u16* __restrict__ B, int ldb,
    const float* __restrict__ bias, void* __restrict__ C, int ldc, int K, float scale)
{
    const int m0 = blockIdx.x << 7;
    const int n0 = blockIdx.y << 7;
    __shared__ u16 smem[24576];
    mgemm_body<EPI>(A, lda, B, ldb, bias, C, ldc, 0, K, scale, m0, n0, smem);
}

// block-causal score GEMM: triangular grid of 528 blocks, z -> (bx, by<=bx)
__global__ __launch_bounds__(256) void mgemm_tri(
    const u16* __restrict__ A, const u16* __restrict__ B,
    float* __restrict__ C, float scale)
{
    const int z = blockIdx.x;
    int bx = (int)((sqrtf((float)(8 * z + 1)) - 1.0f) * 0.5f);
    while ((bx + 1) * (bx + 2) / 2 <= z) ++bx;
    while (bx * (bx + 1) / 2 > z) --bx;
    const int by = z - bx * (bx + 1) / 2;
    __shared__ u16 smem[24576];
    mgemm_body<0>(A, 512, B, 512, nullptr, C, 4096, 0, 512, scale,
                  bx << 7, by << 7, smem);
}

// split-K partial GEMM: writes raw f32 acc to Cpart + z*RD.
// AVK: Klim = m0+96, chunk balanced per row-block; else uniform chunk.
template<bool AVK>
__global__ __launch_bounds__(256) void mgemm_pk(
    const u16* __restrict__ A, int lda, const u16* __restrict__ B, int ldb,
    float* __restrict__ Cpart, int K, int chunk)
{
    const int m0 = blockIdx.x << 7;
    const int n0 = blockIdx.y << 7;
    const int z  = blockIdx.z;
    const int Klim = AVK ? (m0 + 96) : K;
    const int ch = AVK ? ((((Klim >> 2) + 31) >> 5) << 5) : chunk;
    int kBeg = z * ch; if (kBeg > Klim) kBeg = Klim;
    int kEnd = kBeg + ch; if (kEnd > Klim) kEnd = Klim;
    __shared__ u16 smem[24576];
    mgemm_body<0>(A, lda, B, ldb, nullptr, Cpart + (size_t)z * RD, 512,
                  kBeg, kEnd, 1.f, m0, n0, smem);
}

// fused QKV: grid.y = which*4 + n_block.  q,k: bf16+bias; v: bf16+bias transposed
__global__ __launch_bounds__(256) void qkv_gemm(
    const u16* __restrict__ xa, const u16* __restrict__ cfb,
    const u16* __restrict__ Wqb, const u16* __restrict__ Wkb, const u16* __restrict__ Wvb,
    const float* __restrict__ bq, const float* __restrict__ bk, const float* __restrict__ bv,
    u16* __restrict__ q, u16* __restrict__ k, u16* __restrict__ vT)
{
    __shared__ u16 smem[24576];
    const int m0 = blockIdx.x << 7;
    const int which = blockIdx.y >> 2;
    const int n0 = (blockIdx.y & 3) << 7;
    if (which == 0)
        mgemm_body<2>(xa,  512, Wqb, 512, bq, q,  512,  0, 512, 1.f, m0, n0, smem);
    else if (which == 1)
        mgemm_body<2>(cfb, 512, Wkb, 512, bk, k,  512,  0, 512, 1.f, m0, n0, smem);
    else
        mgemm_body<4>(cfb, 512, Wvb, 512, bv, vT, 4096, 0, 512, 1.f, m0, n0, smem);
}

// ---------------- masked row softmax: s(f32) -> p(bf16), zero ragged edge ---
__global__ __launch_bounds__(256) void softmax_pbf(
    const float* __restrict__ S, u16* __restrict__ P)
{
    const int row = blockIdx.x;
    const int b   = row >> 5;
    const int Lb  = b << 5;
    const int bound = ((row >> 7) << 7) + 96;   // AV gemm K bound for this block
    const float* s = S + (size_t)row * 4096;
    u16* p = P + (size_t)row * 4096;

    for (int m = Lb + threadIdx.x; m < bound; m += 256) p[m] = 0;
    if (b == 0) return;

    __shared__ float red[4];
    float mx = -3.0e38f;
    for (int m = threadIdx.x; m < Lb; m += 256) mx = fmaxf(mx, s[m]);
    #pragma unroll
    for (int off = 32; off; off >>= 1) mx = fmaxf(mx, __shfl_xor(mx, off));
    if ((threadIdx.x & 63) == 0) red[threadIdx.x >> 6] = mx;
    __syncthreads();
    mx = fmaxf(fmaxf(red[0], red[1]), fmaxf(red[2], red[3]));
    __syncthreads();

    float sum = 0.f;
    for (int m = threadIdx.x; m < Lb; m += 256) {
        const float e = expf(s[m] - mx);
        p[m] = f2bf(e);
        sum += e;
    }
    #pragma unroll
    for (int off = 32; off; off >>= 1) sum += __shfl_xor(sum, off);
    if ((threadIdx.x & 63) == 0) red[threadIdx.x >> 6] = sum;
    __syncthreads();
    sum = red[0] + red[1] + red[2] + red[3];
    const float inv = 1.0f / sum;
    for (int m = threadIdx.x; m < Lb; m += 256) p[m] = f2bf(bf2f(p[m]) * inv);
}

// ------- x = LN(xin + sum_s part[s] (+bias)); writes f32 x and bf16 copy ----
template<int NS, bool HASB>
__global__ __launch_bounds__(256) void ln_res_ps(
    const float* __restrict__ Xin, const float* __restrict__ part,
    const float* __restrict__ bias,
    const float* __restrict__ gamma, const float* __restrict__ beta,
    float* __restrict__ Xout, u16* __restrict__ Xbf)
{
    const int row  = blockIdx.x * 4 + (threadIdx.x >> 6);
    const int lane = threadIdx.x & 63;
    const float* xr = Xin + (size_t)row * DIM;
    const int d0 = lane << 3;

    const float4 x0 = *reinterpret_cast<const float4*>(&xr[d0]);
    const float4 x1 = *reinterpret_cast<const float4*>(&xr[d0 + 4]);
    float v[8] = {x0.x, x0.y, x0.z, x0.w, x1.x, x1.y, x1.z, x1.w};
    #pragma unroll
    for (int s = 0; s < NS; ++s) {
        const float* pr = part + (size_t)s * RD + (size_t)row * DIM + d0;
        const float4 p0 = *reinterpret_cast<const float4*>(pr);
        const float4 p1 = *reinterpret_cast<const float4*>(pr + 4);
        v[0] += p0.x; v[1] += p0.y; v[2] += p0.z; v[3] += p0.w;
        v[4] += p1.x; v[5] += p1.y; v[6] += p1.z; v[7] += p1.w;
    }
    if (HASB) {
        const float4 b0 = *reinterpret_cast<const float4*>(&bias[d0]);
        const float4 b1 = *reinterpret_cast<const float4*>(&bias[d0 + 4]);
        v[0] += b0.x; v[1] += b0.y; v[2] += b0.z; v[3] += b0.w;
        v[4] += b1.x; v[5] += b1.y; v[6] += b1.z; v[7] += b1.w;
    }

    float sm = 0.f;
    #pragma unroll
    for (int i = 0; i < 8; ++i) sm += v[i];
    #pragma unroll
    for (int off = 32; off; off >>= 1) sm += __shfl_xor(sm, off);
    const float mu = sm * (1.0f / 512.0f);

    float qs = 0.f;
    #pragma unroll
    for (int i = 0; i < 8; ++i) { const float d = v[i] - mu; qs += d * d; }
    #pragma unroll
    for (int off = 32; off; off >>= 1) qs += __shfl_xor(qs, off);
    const float rs = rsqrtf(qs * (1.0f / 512.0f) + 1e-5f);

    const float4 g0 = *reinterpret_cast<const float4*>(&gamma[d0]);
    const float4 g1 = *reinterpret_cast<const float4*>(&gamma[d0 + 4]);
    const float4 b0 = *reinterpret_cast<const float4*>(&beta[d0]);
    const float4 b1 = *reinterpret_cast<const float4*>(&beta[d0 + 4]);
    float o[8];
    o[0] = (v[0] - mu) * rs * g0.x + b0.x;
    o[1] = (v[1] - mu) * rs * g0.y + b0.y;
    o[2] = (v[2] - mu) * rs * g0.z + b0.z;
    o[3] = (v[3] - mu) * rs * g0.w + b0.w;
    o[4] = (v[4] - mu) * rs * g1.x + b1.x;
    o[5] = (v[5] - mu) * rs * g1.y + b1.y;
    o[6] = (v[6] - mu) * rs * g1.z + b1.z;
    o[7] = (v[7] - mu) * rs * g1.w + b1.w;

    float4 f0 = {o[0], o[1], o[2], o[3]}, f1 = {o[4], o[5], o[6], o[7]};
    *reinterpret_cast<float4*>(&Xout[(size_t)row * DIM + d0])     = f0;
    *reinterpret_cast<float4*>(&Xout[(size_t)row * DIM + d0 + 4]) = f1;
    u16x8 ob;
    #pragma unroll
    for (int i = 0; i < 8; ++i) ob[i] = f2bf(o[i]);
    *reinterpret_cast<u16x8*>(&Xbf[(size_t)row * DIM + d0]) = ob;
}

// ---------------- fused f32->bf16 conversion for 7 arrays -------------------
struct ConvArgs {
    const float* src[7];
    u16* dst[7];
    int start[8];      // block-index prefix
};

__global__ __launch_bounds__(256) void conv_all(ConvArgs a)
{
    const int b = blockIdx.x;
    int seg = 0;
    #pragma unroll
    for (int i = 1; i < 7; ++i) seg += (a.start[i] <= b) ? 1 : 0;
    const int i = ((b - a.start[seg]) * 256 + threadIdx.x) << 3;
    const float* s = a.src[seg];
    const float4 lo = *reinterpret_cast<const float4*>(&s[i]);
    const float4 hi = *reinterpret_cast<const float4*>(&s[i + 4]);
    u16x8 o = {f2bf(lo.x), f2bf(lo.y), f2bf(lo.z), f2bf(lo.w),
               f2bf(hi.x), f2bf(hi.y), f2bf(hi.z), f2bf(hi.w)};
    *reinterpret_cast<u16x8*>(&a.dst[seg][i]) = o;
}

// ---------------- small helpers ---------------------------------------------
__global__ __launch_bounds__(256) void fix_x0(u16* __restrict__ xbf,
                                              const u16* __restrict__ cfb)
{
    const int i = (blockIdx.x * 256 + threadIdx.x) << 3;   // 16384 elems total
    *reinterpret_cast<u16x8*>(&xbf[i]) =
        *reinterpret_cast<const u16x8*>(&cfb[i]);
}

__global__ __launch_bounds__(256) void build_cat(
    u16* __restrict__ cat, const u16* __restrict__ cfb, const u16* __restrict__ xbf)
{
    const int idx = blockIdx.x * 256 + threadIdx.x;
    const int row = idx >> 7;
    const int c8  = idx & 127;
    const u16x8 v = (c8 < 64)
        ? *reinterpret_cast<const u16x8*>(&cfb[(size_t)row * 512 + (c8 << 3)])
        : *reinterpret_cast<const u16x8*>(&xbf[(size_t)row * 512 + ((c8 - 64) << 3)]);
    *reinterpret_cast<u16x8*>(&cat[(size_t)row * 1024 + (c8 << 3)]) = v;
}

// out = g*cf + (1-g)*attn, g = sigmoid(part0+part1+bias), attn = (row<32? cf : x)
__global__ __launch_bounds__(256) void final_gate_ps(
    float4* __restrict__ out, const float4* __restrict__ cf,
    const float4* __restrict__ x, const float* __restrict__ part,
    const float* __restrict__ bias)
{
    const int idx = blockIdx.x * 256 + threadIdx.x;   // 524288 float4
    const int row = idx >> 7;
    const int c4  = idx & 127;
    const float4 zc = cf[idx];
    const float4 p0 = reinterpret_cast<const float4*>(part)[idx];
    const float4 p1 = reinterpret_cast<const float4*>(part + RD)[idx];
    const float4 bb = *reinterpret_cast<const float4*>(&bias[c4 << 2]);
    const float4 za = (row < 32) ? zc : x[idx];
    float4 o;
    { const float g = 1.0f / (1.0f + expf(-(p0.x + p1.x + bb.x))); o.x = g * zc.x + (1.0f - g) * za.x; }
    { const float g = 1.0f / (1.0f + expf(-(p0.y + p1.y + bb.y))); o.y = g * zc.y + (1.0f - g) * za.y; }
    { const float g = 1.0f / (1.0f + expf(-(p0.z + p1.z + bb.z))); o.z = g * zc.z + (1.0f - g) * za.z; }
    { const float g = 1.0f / (1.0f + expf(-(p0.w + p1.w + bb.w))); o.w = g * zc.w + (1.0f - g) * za.w; }
    out[idx] = o;
}

// ---------------------------------------------------------------------------
extern "C" void kernel_launch(void* const* d_in, const int* in_sizes, int n_in,
                              void* d_out, int out_size, void* d_ws, size_t ws_size,
                              hipStream_t stream)
{
    const float* cf   = (const float*)d_in[0];
    const float* Wq   = (const float*)d_in[1];
    const float* bq   = (const float*)d_in[2];
    const float* Wk   = (const float*)d_in[3];
    const float* bk   = (const float*)d_in[4];
    const float* Wv   = (const float*)d_in[5];
    const float* bv   = (const float*)d_in[6];
    const float* ln1g = (const float*)d_in[7];
    const float* ln1b = (const float*)d_in[8];
    const float* W1   = (const float*)d_in[9];
    const float* b1   = (const float*)d_in[10];
    const float* W2   = (const float*)d_in[11];
    const float* b2   = (const float*)d_in[12];
    const float* ln2g = (const float*)d_in[13];
    const float* ln2b = (const float*)d_in[14];
    const float* Wsg  = (const float*)d_in[15];
    const float* bsg  = (const float*)d_in[16];
    float* out = (float*)d_out;

    float* ws  = (float*)d_ws;
    float* x   = ws;                                // [4096,512] f32
    float* s   = ws + 2 * RD;                       // [4096,4096] f32 (attn phase)
    float* part= ws + 2 * RD;                       // 4x[4096,512] f32 partials
                                                    // (aliases s; s dead then)
    u16*  pbf  = (u16*)(ws + 10 * RD);              // shared: p / h / cat (bf16)
    u16*  hbf  = pbf;
    u16*  catb = pbf;
    u16*  bfb  = (u16*)(ws + 14 * RD);
    u16* cfb = bfb;                                 // [4096,512]
    u16* xbf = bfb + RD;
    u16* qbf = bfb + 2 * RD;
    u16* kbf = bfb + 3 * RD;
    u16* vTb = bfb + 4 * RD;                        // [512,4096] (V transposed)
    u16* Wqb = bfb + 5 * RD;
    u16* Wkb = Wqb + 524288;
    u16* Wvb = Wkb + 524288;
    u16* W1b = Wvb + 524288;
    u16* W2b = W1b + 2097152;
    u16* Wsb = W2b + 2097152;

    const float scale = 0.044194173824159216f;      // 1/sqrt(512)

    ConvArgs ca;
    ca.src[0] = cf;  ca.dst[0] = cfb;
    ca.src[1] = Wq;  ca.dst[1] = Wqb;
    ca.src[2] = Wk;  ca.dst[2] = Wkb;
    ca.src[3] = Wv;  ca.dst[3] = Wvb;
    ca.src[4] = W1;  ca.dst[4] = W1b;
    ca.src[5] = W2;  ca.dst[5] = W2b;
    ca.src[6] = Wsg; ca.dst[6] = Wsb;
    ca.start[0] = 0;    ca.start[1] = 1024; ca.start[2] = 1280;
    ca.start[3] = 1536; ca.start[4] = 1792; ca.start[5] = 2816;
    ca.start[6] = 3840; ca.start[7] = 4096;
    conv_all<<<4096, 256, 0, stream>>>(ca);

    for (int l = 0; l < 2; ++l) {
        const u16* xa = (l == 0) ? cfb : xbf;
        qkv_gemm<<<dim3(32, 12), 256, 0, stream>>>(
            xa, cfb, Wqb + l * 262144, Wkb + l * 262144, Wvb + l * 262144,
            bq + l * 512, bk + l * 512, bv + l * 512, qbf, kbf, vTb);
        mgemm_tri<<<528, 256, 0, stream>>>(qbf, kbf, s, scale);
        softmax_pbf<<<4096, 256, 0, stream>>>(s, pbf);
        // AV: split-K 4, balanced per row-block (s region dead -> partials alias)
        mgemm_pk<true><<<dim3(32, 4, 4), 256, 0, stream>>>(
            pbf, 4096, vTb, 4096, part, 4096, 0);
        ln_res_ps<4, false><<<1024, 256, 0, stream>>>(
            (l == 0) ? cf : x, part, nullptr, ln1g + l * 512, ln1b + l * 512, x, xbf);
        mgemm<3><<<dim3(32, 16), 256, 0, stream>>>(
            xbf, 512, W1b + l * 1048576, 512, b1 + l * 2048, hbf, 2048, 512, 1.f);
        // MLP2: split-K 4 x 512
        mgemm_pk<false><<<dim3(32, 4, 4), 256, 0, stream>>>(
            hbf, 2048, W2b + l * 1048576, 2048, part, 2048, 512);
        ln_res_ps<4, true><<<1024, 256, 0, stream>>>(
            x, part, b2 + l * 512, ln2g + l * 512, ln2b + l * 512, x, xbf);
    }

    fix_x0<<<8, 256, 0, stream>>>(xbf, cfb);              // attn_out rows 0..31 = cf
    build_cat<<<2048, 256, 0, stream>>>(catb, cfb, xbf);
    // gate: split-K 2 x 512
    mgemm_pk<false><<<dim3(32, 4, 2), 256, 0, stream>>>(
        catb, 1024, Wsb, 1024, part, 1024, 512);
    final_gate_ps<<<2048, 256, 0, stream>>>((float4*)out, (const float4*)cf,
                                            (const float4*)x, part, bsg);
}

// Round 5
// 318.623 us; speedup vs baseline: 5.4368x; 1.0009x over previous
//
#include <hip/hip_runtime.h>
#include <cmath>

// ---------------------------------------------------------------------------
// MemoryBankV2: B=128, T=32, D=512, L=2.  Rows = B*T = 4096.
// Round 5: BM=64 x BN=128 tiles (4 blocks/CU, 16 waves/CU) to fix the
// occupancy ceiling of R4 (2 blocks/CU).  Depth-2 counted-vmcnt pipeline,
// triple-buffered LDS (36KB), finer 64-row triangular score grid, split-K
// skinny GEMMs with fused reductions.
// ---------------------------------------------------------------------------

#define ROWS 4096
#define DIM  512

typedef __bf16 bf16x8 __attribute__((ext_vector_type(8)));
typedef float  f32x4  __attribute__((ext_vector_type(4)));
typedef unsigned short u16;
typedef u16 u16x4 __attribute__((ext_vector_type(4)));
typedef u16 u16x8 __attribute__((ext_vector_type(8)));

#define RD ((size_t)ROWS * DIM)
// buffer layout (u16 units): A tile 64x32 = 2048, B tile 128x32 = 4096
#define BUFU 6144

__device__ __forceinline__ u16 f2bf(float x) {
    union { float f; unsigned u; } c; c.f = x;
    const unsigned r = (c.u + 0x7FFFu + ((c.u >> 16) & 1u)) >> 16;
    return (u16)r;
}
__device__ __forceinline__ float bf2f(u16 h) {
    union { unsigned u; float f; } c; c.u = ((unsigned)h) << 16;
    return c.f;
}

__device__ __forceinline__ void gload16(const void* g, void* l) {
    __builtin_amdgcn_global_load_lds(
        (const __attribute__((address_space(1))) void*)g,
        (__attribute__((address_space(3))) void*)l, 16, 0, 0);
}

// ---------------- MFMA GEMM body --------------------------------------------
// C[M,N] = epi(A[M,K] @ B[N,K]^T), K range [kBeg,kEnd), 64x128 tile, BK=32.
// LDS slot (16B) = row*4 + (kg ^ ((row>>1)&3)); triple-buffered, depth-2
// prefetch with counted vmcnt(3) so one tile's 3 loads stay in flight.
// EPI: 0: f32 = acc*scale | 1: f32 = acc+bias | 2: bf16 = acc+bias
//      3: bf16 = gelu(acc+bias) | 4: bf16 transposed (C[col*ldc+row]) = acc+bias
template<int EPI>
__device__ __forceinline__ void mgemm_body(
    const u16* __restrict__ A, int lda,
    const u16* __restrict__ B, int ldb,
    const float* __restrict__ bias,
    void* __restrict__ C, int ldc,
    int kBeg, int kEnd, float scale, int m0, int n0, u16* smem)
{
    const int tid  = threadIdx.x;
    const int lane = tid & 63;
    const int w    = tid >> 6;          // wave 0..3 (2x2 over 64x128 tile)
    const int wr   = (w >> 1) << 5;     // wave row base: 0 or 32
    const int wc   = (w & 1) << 6;      // wave col base: 0 or 64

    f32x4 acc[2][4];
    #pragma unroll
    for (int i = 0; i < 2; ++i)
        #pragma unroll
        for (int j = 0; j < 4; ++j)
            acc[i][j] = (f32x4){0.f, 0.f, 0.f, 0.f};

    // staging: A slot = tid (256 slots); B slots = tid, tid+256 (512 slots)
    const int ra  = tid >> 2, ga  = (tid & 3) ^ ((ra >> 1) & 3);
    const int rb0 = ra,       gb0 = ga;
    const int sb1 = tid + 256;
    const int rb1 = sb1 >> 2, gb1 = (sb1 & 3) ^ ((rb1 >> 1) & 3);
    const u16* pA  = A + (size_t)(m0 + ra)  * lda + (ga  << 3) + kBeg;
    const u16* pB0 = B + (size_t)(n0 + rb0) * ldb + (gb0 << 3) + kBeg;
    const u16* pB1 = B + (size_t)(n0 + rb1) * ldb + (gb1 << 3) + kBeg;
    const int wofs = w << 9;            // wave's lane-contiguous chunk (u16)

    // fragment LDS offsets (within buffer, k-step independent)
    const int l15 = lane & 15, kg = lane >> 4;
    int aoff[2], boff[4];
    #pragma unroll
    for (int i = 0; i < 2; ++i) {
        const int r = wr + (i << 4) + l15;
        aoff[i] = (((r << 2) + (kg ^ ((r >> 1) & 3))) << 3);
    }
    #pragma unroll
    for (int j = 0; j < 4; ++j) {
        const int c = wc + (j << 4) + l15;
        boff[j] = 2048 + (((c << 2) + (kg ^ ((c >> 1) & 3))) << 3);
    }

    const int nt = (kEnd - kBeg) >> 5;

    if (nt > 0) {
        // prologue: stage tiles 0 (buf0) and 1 (buf1)
        {
            u16* bb = smem + wofs;
            gload16(pA,  bb);
            gload16(pB0, bb + 2048);
            gload16(pB1, bb + 4096);
        }
        if (nt > 1) {
            u16* bb = smem + BUFU + wofs;
            gload16(pA + 32,  bb);
            gload16(pB0 + 32, bb + 2048);
            gload16(pB1 + 32, bb + 4096);
        }
        int bread = 0;                  // buffer holding tile t
        for (int t = 0; t < nt; ++t) {
            // wait for tile t's 3 loads (leave tile t+1's 3 in flight)
            if (t == nt - 1) asm volatile("s_waitcnt vmcnt(0)" ::: "memory");
            else             asm volatile("s_waitcnt vmcnt(3)" ::: "memory");
            __builtin_amdgcn_s_barrier();
            asm volatile("" ::: "memory");   // pin LDS ops below barrier

            if (t + 2 < nt) {            // stage tile t+2 into freed buffer
                const int bst = (bread == 0) ? 2 : bread - 1;
                const int ko = (t + 2) << 5;
                u16* bb = smem + bst * BUFU + wofs;
                gload16(pA + ko,  bb);
                gload16(pB0 + ko, bb + 2048);
                gload16(pB1 + ko, bb + 4096);
            }

            const u16* buf = smem + bread * BUFU;
            bf16x8 af[2], bfr[4];
            #pragma unroll
            for (int i = 0; i < 2; ++i) af[i]  = *reinterpret_cast<const bf16x8*>(&buf[aoff[i]]);
            #pragma unroll
            for (int j = 0; j < 4; ++j) bfr[j] = *reinterpret_cast<const bf16x8*>(&buf[boff[j]]);

            __builtin_amdgcn_s_setprio(1);
            #pragma unroll
            for (int i = 0; i < 2; ++i)
                #pragma unroll
                for (int j = 0; j < 4; ++j)
                    acc[i][j] = __builtin_amdgcn_mfma_f32_16x16x32_bf16(af[i], bfr[j], acc[i][j], 0, 0, 0);
            __builtin_amdgcn_s_setprio(0);

            bread = (bread == 2) ? 0 : bread + 1;
        }
    }

    // epilogue: C/D frag layout: col = lane&15, row = (lane>>4)*4 + reg
    const int lq = lane >> 4;
    #pragma unroll
    for (int j = 0; j < 4; ++j) {
        const int col = n0 + wc + (j << 4) + l15;
        const float bj = (EPI != 0) ? bias[col] : 0.f;
        #pragma unroll
        for (int i = 0; i < 2; ++i) {
            const int row0 = m0 + wr + (i << 4) + (lq << 2);
            if (EPI == 4) {
                u16x4 pk;
                #pragma unroll
                for (int r = 0; r < 4; ++r) pk[r] = f2bf(acc[i][j][r] + bj);
                *reinterpret_cast<u16x4*>(&((u16*)C)[(size_t)col * ldc + row0]) = pk;
            } else {
                #pragma unroll
                for (int r = 0; r < 4; ++r) {
                    float v = acc[i][j][r];
                    if (EPI == 0) v *= scale; else v += bj;
                    if (EPI == 3) v = 0.5f * v * (1.0f + erff(v * 0.70710678118654752f));
                    if (EPI == 0 || EPI == 1)
                        ((float*)C)[(size_t)(row0 + r) * ldc + col] = v;
                    else
                        ((u16*)C)[(size_t)(row0 + r) * ldc + col] = f2bf(v);
                }
            }
        }
    }
}

template<int EPI>
__global__ __launch_bounds__(256, 4) void mgemm(
    const u16* __restrict__ A, int lda, const u16* __restrict__ B, int ldb,
    const float* __restrict__ bias, void* __restrict__ C, int ldc, int K, float scale)
{
    const int m0 = blockIdx.x << 6;
    const int n0 = blockIdx.y << 7;
    __shared__ u16 smem[3 * BUFU];
    mgemm_body<EPI>(A, lda, B, ldb, bias, C, ldc, 0, K, scale, m0, n0, smem);
}

// block-causal score GEMM: 64-row x 128-col tiles; tile (bx,by) live iff
// 128*by < 64*bx + 32  <=>  by <= bx>>1.  count(bx) = (bx>>1)+1, total 1056.
__device__ __forceinline__ int tri_pref(int b) {
    const int h = b >> 1;
    return (b & 1) ? (h + 1) * (h + 1) : h * (h + 1);
}
__global__ __launch_bounds__(256, 4) void mgemm_tri(
    const u16* __restrict__ A, const u16* __restrict__ B,
    float* __restrict__ C, float scale)
{
    const int z = blockIdx.x;
    int bx = 2 * (int)sqrtf((float)z);
    while (tri_pref(bx + 1) <= z) ++bx;
    while (tri_pref(bx) > z) --bx;
    const int by = z - tri_pref(bx);
    __shared__ u16 smem[3 * BUFU];
    mgemm_body<0>(A, 512, B, 512, nullptr, C, 4096, 0, 512, scale,
                  bx << 6, by << 7, smem);
}

// split-K partial GEMM: writes raw f32 acc to Cpart + z*RD.
// AVK: Klim = m0+32 (block-causal), chunk balanced per row-block.
template<bool AVK>
__global__ __launch_bounds__(256, 4) void mgemm_pk(
    const u16* __restrict__ A, int lda, const u16* __restrict__ B, int ldb,
    float* __restrict__ Cpart, int K, int chunk)
{
    const int m0 = blockIdx.x << 6;
    const int n0 = blockIdx.y << 7;
    const int z  = blockIdx.z;
    const int Klim = AVK ? (m0 + 32) : K;
    const int ch = AVK ? ((((Klim >> 2) + 31) >> 5) << 5) : chunk;
    int kBeg = z * ch; if (kBeg > Klim) kBeg = Klim;
    int kEnd = kBeg + ch; if (kEnd > Klim) kEnd = Klim;
    __shared__ u16 smem[3 * BUFU];
    mgemm_body<0>(A, lda, B, ldb, nullptr, Cpart + (size_t)z * RD, 512,
                  kBeg, kEnd, 1.f, m0, n0, smem);
}

// fused QKV: grid.y = which*4 + n_block.  q,k: bf16+bias; v: bf16+bias transposed
__global__ __launch_bounds__(256, 4) void qkv_gemm(
    const u16* __restrict__ xa, const u16* __restrict__ cfb,
    const u16* __restrict__ Wqb, const u16* __restrict__ Wkb, const u16* __restrict__ Wvb,
    const float* __restrict__ bq, const float* __restrict__ bk, const float* __restrict__ bv,
    u16* __restrict__ q, u16* __restrict__ k, u16* __restrict__ vT)
{
    __shared__ u16 smem[3 * BUFU];
    const int m0 = blockIdx.x << 6;
    const int which = blockIdx.y >> 2;
    const int n0 = (blockIdx.y & 3) << 7;
    if (which == 0)
        mgemm_body<2>(xa,  512, Wqb, 512, bq, q,  512,  0, 512, 1.f, m0, n0, smem);
    else if (which == 1)
        mgemm_body<2>(cfb, 512, Wkb, 512, bk, k,  512,  0, 512, 1.f, m0, n0, smem);
    else
        mgemm_body<4>(cfb, 512, Wvb, 512, bv, vT, 4096, 0, 512, 1.f, m0, n0, smem);
}

// ---------------- masked row softmax: s(f32) -> p(bf16), zero ragged edge ---
__global__ __launch_bounds__(256) void softmax_pbf(
    const float* __restrict__ S, u16* __restrict__ P)
{
    const int row = blockIdx.x;
    const int b   = row >> 5;
    const int Lb  = b << 5;
    const int bound = ((row >> 6) << 6) + 32;   // AV K bound for 64-row block
    const float* s = S + (size_t)row * 4096;
    u16* p = P + (size_t)row * 4096;

    for (int m = Lb + threadIdx.x; m < bound; m += 256) p[m] = 0;
    if (b == 0) return;

    __shared__ float red[4];
    float mx = -3.0e38f;
    for (int m = threadIdx.x; m < Lb; m += 256) mx = fmaxf(mx, s[m]);
    #pragma unroll
    for (int off = 32; off; off >>= 1) mx = fmaxf(mx, __shfl_xor(mx, off));
    if ((threadIdx.x & 63) == 0) red[threadIdx.x >> 6] = mx;
    __syncthreads();
    mx = fmaxf(fmaxf(red[0], red[1]), fmaxf(red[2], red[3]));
    __syncthreads();

    float sum = 0.f;
    for (int m = threadIdx.x; m < Lb; m += 256) {
        const float e = expf(s[m] - mx);
        p[m] = f2bf(e);
        sum += e;
    }
    #pragma unroll
    for (int off = 32; off; off >>= 1) sum += __shfl_xor(sum, off);
    if ((threadIdx.x & 63) == 0) red[threadIdx.x >> 6] = sum;
    __syncthreads();
    sum = red[0] + red[1] + red[2] + red[3];
    const float inv = 1.0f / sum;
    for (int m = threadIdx.x; m < Lb; m += 256) p[m] = f2bf(bf2f(p[m]) * inv);
}

// ------- x = LN(xin + sum_s part[s] (+bias)); writes f32 x and bf16 copy ----
template<int NS, bool HASB>
__global__ __launch_bounds__(256) void ln_res_ps(
    const float* __restrict__ Xin, const float* __restrict__ part,
    const float* __restrict__ bias,
    const float* __restrict__ gamma, const float* __restrict__ beta,
    float* __restrict__ Xout, u16* __restrict__ Xbf)
{
    const int row  = blockIdx.x * 4 + (threadIdx.x >> 6);
    const int lane = threadIdx.x & 63;
    const float* xr = Xin + (size_t)row * DIM;
    const int d0 = lane << 3;

    const float4 x0 = *reinterpret_cast<const float4*>(&xr[d0]);
    const float4 x1 = *reinterpret_cast<const float4*>(&xr[d0 + 4]);
    float v[8] = {x0.x, x0.y, x0.z, x0.w, x1.x, x1.y, x1.z, x1.w};
    #pragma unroll
    for (int s = 0; s < NS; ++s) {
        const float* pr = part + (size_t)s * RD + (size_t)row * DIM + d0;
        const float4 p0 = *reinterpret_cast<const float4*>(pr);
        const float4 p1 = *reinterpret_cast<const float4*>(pr + 4);
        v[0] += p0.x; v[1] += p0.y; v[2] += p0.z; v[3] += p0.w;
        v[4] += p1.x; v[5] += p1.y; v[6] += p1.z; v[7] += p1.w;
    }
    if (HASB) {
        const float4 b0 = *reinterpret_cast<const float4*>(&bias[d0]);
        const float4 b1 = *reinterpret_cast<const float4*>(&bias[d0 + 4]);
        v[0] += b0.x; v[1] += b0.y; v[2] += b0.z; v[3] += b0.w;
        v[4] += b1.x; v[5] += b1.y; v[6] += b1.z; v[7] += b1.w;
    }

    float sm = 0.f;
    #pragma unroll
    for (int i = 0; i < 8; ++i) sm += v[i];
    #pragma unroll
    for (int off = 32; off; off >>= 1) sm += __shfl_xor(sm, off);
    const float mu = sm * (1.0f / 512.0f);

    float qs = 0.f;
    #pragma unroll
    for (int i = 0; i < 8; ++i) { const float d = v[i] - mu; qs += d * d; }
    #pragma unroll
    for (int off = 32; off; off >>= 1) qs += __shfl_xor(qs, off);
    const float rs = rsqrtf(qs * (1.0f / 512.0f) + 1e-5f);

    const float4 g0 = *reinterpret_cast<const float4*>(&gamma[d0]);
    const float4 g1 = *reinterpret_cast<const float4*>(&gamma[d0 + 4]);
    const float4 b0 = *reinterpret_cast<const float4*>(&beta[d0]);
    const float4 b1 = *reinterpret_cast<const float4*>(&beta[d0 + 4]);
    float o[8];
    o[0] = (v[0] - mu) * rs * g0.x + b0.x;
    o[1] = (v[1] - mu) * rs * g0.y + b0.y;
    o[2] = (v[2] - mu) * rs * g0.z + b0.z;
    o[3] = (v[3] - mu) * rs * g0.w + b0.w;
    o[4] = (v[4] - mu) * rs * g1.x + b1.x;
    o[5] = (v[5] - mu) * rs * g1.y + b1.y;
    o[6] = (v[6] - mu) * rs * g1.z + b1.z;
    o[7] = (v[7] - mu) * rs * g1.w + b1.w;

    float4 f0 = {o[0], o[1], o[2], o[3]}, f1 = {o[4], o[5], o[6], o[7]};
    *reinterpret_cast<float4*>(&Xout[(size_t)row * DIM + d0])     = f0;
    *reinterpret_cast<float4*>(&Xout[(size_t)row * DIM + d0 + 4]) = f1;
    u16x8 ob;
    #pragma unroll
    for (int i = 0; i < 8; ++i) ob[i] = f2bf(o[i]);
    *reinterpret_cast<u16x8*>(&Xbf[(size_t)row * DIM + d0]) = ob;
}

// ---------------- fused f32->bf16 conversion for 7 arrays -------------------
struct ConvArgs {
    const float* src[7];
    u16* dst[7];
    int start[8];      // block-index prefix
};

__global__ __launch_bounds__(256) void conv_all(ConvArgs a)
{
    const int b = blockIdx.x;
    int seg = 0;
    #pragma unroll
    for (int i = 1; i < 7; ++i) seg += (a.start[i] <= b) ? 1 : 0;
    const int i = ((b - a.start[seg]) * 256 + threadIdx.x) << 3;
    const float* s = a.src[seg];
    const float4 lo = *reinterpret_cast<const float4*>(&s[i]);
    const float4 hi = *reinterpret_cast<const float4*>(&s[i + 4]);
    u16x8 o = {f2bf(lo.x), f2bf(lo.y), f2bf(lo.z), f2bf(lo.w),
               f2bf(hi.x), f2bf(hi.y), f2bf(hi.z), f2bf(hi.w)};
    *reinterpret_cast<u16x8*>(&a.dst[seg][i]) = o;
}

// ---------------- small helpers ---------------------------------------------
// cat[row] = [cf[row], (row<32 ? cf : x)[row]]
__global__ __launch_bounds__(256) void build_cat(
    u16* __restrict__ cat, const u16* __restrict__ cfb, const u16* __restrict__ xbf)
{
    const int idx = blockIdx.x * 256 + threadIdx.x;
    const int row = idx >> 7;
    const int c8  = idx & 127;
    const u16* src2 = (row < 32) ? cfb : xbf;
    const u16x8 v = (c8 < 64)
        ? *reinterpret_cast<const u16x8*>(&cfb[(size_t)row * 512 + (c8 << 3)])
        : *reinterpret_cast<const u16x8*>(&src2[(size_t)row * 512 + ((c8 - 64) << 3)]);
    *reinterpret_cast<u16x8*>(&cat[(size_t)row * 1024 + (c8 << 3)]) = v;
}

// out = g*cf + (1-g)*attn, g = sigmoid(part0+part1+bias), attn = (row<32? cf : x)
__global__ __launch_bounds__(256) void final_gate_ps(
    float4* __restrict__ out, const float4* __restrict__ cf,
    const float4* __restrict__ x, const float* __restrict__ part,
    const float* __restrict__ bias)
{
    const int idx = blockIdx.x * 256 + threadIdx.x;   // 524288 float4
    const int row = idx >> 7;
    const int c4  = idx & 127;
    const float4 zc = cf[idx];
    const float4 p0 = reinterpret_cast<const float4*>(part)[idx];
    const float4 p1 = reinterpret_cast<const float4*>(part + RD)[idx];
    const float4 bb = *reinterpret_cast<const float4*>(&bias[c4 << 2]);
    const float4 za = (row < 32) ? zc : x[idx];
    float4 o;
    { const float g = 1.0f / (1.0f + expf(-(p0.x + p1.x + bb.x))); o.x = g * zc.x + (1.0f - g) * za.x; }
    { const float g = 1.0f / (1.0f + expf(-(p0.y + p1.y + bb.y))); o.y = g * zc.y + (1.0f - g) * za.y; }
    { const float g = 1.0f / (1.0f + expf(-(p0.z + p1.z + bb.z))); o.z = g * zc.z + (1.0f - g) * za.z; }
    { const float g = 1.0f / (1.0f + expf(-(p0.w + p1.w + bb.w))); o.w = g * zc.w + (1.0f - g) * za.w; }
    out[idx] = o;
}

// ---------------------------------------------------------------------------
extern "C" void kernel_launch(void* const* d_in, const int* in_sizes, int n_in,
                              void* d_out, int out_size, void* d_ws, size_t ws_size,
                              hipStream_t stream)
{
    const float* cf   = (const float*)d_in[0];
    const float* Wq   = (const float*)d_in[1];
    const float* bq   = (const float*)d_in[2];
    const float* Wk   = (const float*)d_in[3];
    const float* bk   = (const float*)d_in[4];
    const float* Wv   = (const float*)d_in[5];
    const float* bv   = (const float*)d_in[6];
    const float* ln1g = (const float*)d_in[7];
    const float* ln1b = (const float*)d_in[8];
    const float* W1   = (const float*)d_in[9];
    const float* b1   = (const float*)d_in[10];
    const float* W2   = (const float*)d_in[11];
    const float* b2   = (const float*)d_in[12];
    const float* ln2g = (const float*)d_in[13];
    const float* ln2b = (const float*)d_in[14];
    const float* Wsg  = (const float*)d_in[15];
    const float* bsg  = (const float*)d_in[16];
    float* out = (float*)d_out;

    float* ws  = (float*)d_ws;
    float* x   = ws;                                // [4096,512] f32
    float* s   = ws + 2 * RD;                       // [4096,4096] f32 (attn phase)
    float* part= ws + 2 * RD;                       // 4x[4096,512] f32 partials
                                                    // (aliases s; s dead then)
    u16*  pbf  = (u16*)(ws + 10 * RD);              // shared: p / h / cat (bf16)
    u16*  hbf  = pbf;
    u16*  catb = pbf;
    u16*  bfb  = (u16*)(ws + 14 * RD);
    u16* cfb = bfb;                                 // [4096,512]
    u16* xbf = bfb + RD;
    u16* qbf = bfb + 2 * RD;
    u16* kbf = bfb + 3 * RD;
    u16* vTb = bfb + 4 * RD;                        // [512,4096] (V transposed)
    u16* Wqb = bfb + 5 * RD;
    u16* Wkb = Wqb + 524288;
    u16* Wvb = Wkb + 524288;
    u16* W1b = Wvb + 524288;
    u16* W2b = W1b + 2097152;
    u16* Wsb = W2b + 2097152;

    const float scale = 0.044194173824159216f;      // 1/sqrt(512)

    ConvArgs ca;
    ca.src[0] = cf;  ca.dst[0] = cfb;
    ca.src[1] = Wq;  ca.dst[1] = Wqb;
    ca.src[2] = Wk;  ca.dst[2] = Wkb;
    ca.src[3] = Wv;  ca.dst[3] = Wvb;
    ca.src[4] = W1;  ca.dst[4] = W1b;
    ca.src[5] = W2;  ca.dst[5] = W2b;
    ca.src[6] = Wsg; ca.dst[6] = Wsb;
    ca.start[0] = 0;    ca.start[1] = 1024; ca.start[2] = 1280;
    ca.start[3] = 1536; ca.start[4] = 1792; ca.start[5] = 2816;
    ca.start[6] = 3840; ca.start[7] = 4096;
    conv_all<<<4096, 256, 0, stream>>>(ca);

    for (int l = 0; l < 2; ++l) {
        const u16* xa = (l == 0) ? cfb : xbf;
        qkv_gemm<<<dim3(64, 12), 256, 0, stream>>>(
            xa, cfb, Wqb + l * 262144, Wkb + l * 262144, Wvb + l * 262144,
            bq + l * 512, bk + l * 512, bv + l * 512, qbf, kbf, vTb);
        mgemm_tri<<<1056, 256, 0, stream>>>(qbf, kbf, s, scale);
        softmax_pbf<<<4096, 256, 0, stream>>>(s, pbf);
        // AV: split-K 4, balanced per row-block (s region dead -> partials alias)
        mgemm_pk<true><<<dim3(64, 4, 4), 256, 0, stream>>>(
            pbf, 4096, vTb, 4096, part, 4096, 0);
        ln_res_ps<4, false><<<1024, 256, 0, stream>>>(
            (l == 0) ? cf : x, part, nullptr, ln1g + l * 512, ln1b + l * 512, x, xbf);
        mgemm<3><<<dim3(64, 16), 256, 0, stream>>>(
            xbf, 512, W1b + l * 1048576, 512, b1 + l * 2048, hbf, 2048, 512, 1.f);
        // MLP2: split-K 4 x 512
        mgemm_pk<false><<<dim3(64, 4, 4), 256, 0, stream>>>(
            hbf, 2048, W2b + l * 1048576, 2048, part, 2048, 512);
        ln_res_ps<4, true><<<1024, 256, 0, stream>>>(
            x, part, b2 + l * 512, ln2g + l * 512, ln2b + l * 512, x, xbf);
    }

    build_cat<<<2048, 256, 0, stream>>>(catb, cfb, xbf);
    // gate: split-K 2 x 512
    mgemm_pk<false><<<dim3(64, 4, 2), 256, 0, stream>>>(
        catb, 1024, Wsb, 1024, part, 1024, 512);
    final_gate_ps<<<2048, 256, 0, stream>>>((float4*)out, (const float4*)cf,
                                            (const float4*)x, part, bsg);
}

// Round 6
// 271.210 us; speedup vs baseline: 6.3873x; 1.1748x over previous
//
#include <hip/hip_runtime.h>
#include <cmath>

// ---------------------------------------------------------------------------
// MemoryBankV2: B=128, T=32, D=512, L=2.  Rows = B*T = 4096.
// Round 6: BK=64 two-barrier phase (counted vmcnt(6), 12 loads in flight,
// 16 MFMA/wave/step), operand-swapped MFMA -> vectorized float4/u16x4
// epilogue stores, 2-pass softmax with fused normalization in ln_res.
// Tiles 64x128, dbuf LDS 48KB, 3 blocks/CU.
// ---------------------------------------------------------------------------

#define ROWS 4096
#define DIM  512

typedef __bf16 bf16x8 __attribute__((ext_vector_type(8)));
typedef float  f32x4  __attribute__((ext_vector_type(4)));
typedef unsigned short u16;
typedef u16 u16x4 __attribute__((ext_vector_type(4)));
typedef u16 u16x8 __attribute__((ext_vector_type(8)));

#define RD ((size_t)ROWS * DIM)
#define BUFU 12288   // u16 per LDS buffer: A 64x64 (4096) + B 128x64 (8192)

__device__ __forceinline__ u16 f2bf(float x) {
    union { float f; unsigned u; } c; c.f = x;
    const unsigned r = (c.u + 0x7FFFu + ((c.u >> 16) & 1u)) >> 16;
    return (u16)r;
}

__device__ __forceinline__ void gload16(const void* g, void* l) {
    __builtin_amdgcn_global_load_lds(
        (const __attribute__((address_space(1))) void*)g,
        (__attribute__((address_space(3))) void*)l, 16, 0, 0);
}

__device__ __forceinline__ float gelu_f(float v) {
    return 0.5f * v * (1.0f + erff(v * 0.70710678118654752f));
}

// ---------------- MFMA GEMM body --------------------------------------------
// C[M,N] = epi(A[M,K] @ B[N,K]^T), K range [kBeg,kEnd), 64x128 tile, BK=64.
// LDS 16B-slot layout per tile region: slot(row, subp) holds global k-chunk
// subl = subp ^ (row&7)  (XOR swizzle; conflict-free b128 frag reads).
// Two-barrier phase per K-step, counted vmcnt(6): 12 loads span barriers.
// EPI: 0: f32 = acc*scale | 1: f32 = acc+bias | 2: bf16 = acc+bias
//      3: bf16 = gelu(acc+bias) | 4: bf16 transposed (C[col*ldc+row]) = acc+bias
template<int EPI>
__device__ __forceinline__ void mgemm_body(
    const u16* __restrict__ A, int lda,
    const u16* __restrict__ B, int ldb,
    const float* __restrict__ bias,
    void* __restrict__ C, int ldc,
    int kBeg, int kEnd, float scale, int m0, int n0, u16* smem)
{
    const int tid  = threadIdx.x;
    const int lane = tid & 63;
    const int w    = tid >> 6;          // wave 0..3 (2x2 over 64x128 tile)
    const int wr   = (w >> 1) << 5;     // wave row base: 0 or 32
    const int wc   = (w & 1) << 6;      // wave col base: 0 or 64

    f32x4 acc[2][4];
    #pragma unroll
    for (int i = 0; i < 2; ++i)
        #pragma unroll
        for (int j = 0; j < 4; ++j)
            acc[i][j] = (f32x4){0.f, 0.f, 0.f, 0.f};

    // ---- staging map: 24 chunks of 64 slots; wave w owns chunks q*4+w ----
    // q=0,1 -> A chunks (c in [0,8)); q=2..5 -> B chunks (c-8 in [0,16))
    const u16* gpA[2]; int loA[2];
    #pragma unroll
    for (int q = 0; q < 2; ++q) {
        const int c = (q << 2) + w;
        const int s = (c << 6) + lane;
        const int row = s >> 3, sub = (s & 7) ^ (row & 7);
        gpA[q] = A + (size_t)(m0 + row) * lda + (sub << 3) + kBeg;
        loA[q] = c << 9;                 // u16 offset
    }
    const u16* gpB[4]; int loB[4];
    #pragma unroll
    for (int q = 0; q < 4; ++q) {
        const int c = ((q + 2) << 2) + w - 8;   // B chunk index in [0,16)
        const int s = (c << 6) + lane;
        const int row = s >> 3, sub = (s & 7) ^ (row & 7);
        gpB[q] = B + (size_t)(n0 + row) * ldb + (sub << 3) + kBeg;
        loB[q] = 4096 + (c << 9);
    }

    // ---- fragment LDS offsets (u16 units, within buffer) ----
    const int l15 = lane & 15, kg = lane >> 4;
    int aoff[2][2], boff[4][2];
    #pragma unroll
    for (int i = 0; i < 2; ++i)
        #pragma unroll
        for (int h = 0; h < 2; ++h) {
            const int r = wr + (i << 4) + l15;
            const int sub = ((h << 2) + kg) ^ (r & 7);
            aoff[i][h] = ((r << 3) + sub) << 3;
        }
    #pragma unroll
    for (int j = 0; j < 4; ++j)
        #pragma unroll
        for (int h = 0; h < 2; ++h) {
            const int r = wc + (j << 4) + l15;
            const int sub = ((h << 2) + kg) ^ (r & 7);
            boff[j][h] = 4096 + (((r << 3) + sub) << 3);
        }

    const int nt = (kEnd - kBeg) >> 6;

    auto STAGE = [&](int t, int bsel) {
        u16* base = smem + bsel * BUFU;
        const int ko = t << 6;
        gload16(gpA[0] + ko, base + loA[0]);
        gload16(gpA[1] + ko, base + loA[1]);
        gload16(gpB[0] + ko, base + loB[0]);
        gload16(gpB[1] + ko, base + loB[1]);
        gload16(gpB[2] + ko, base + loB[2]);
        gload16(gpB[3] + ko, base + loB[3]);
    };

    if (nt > 0) {
        STAGE(0, 0);
        if (nt > 1) STAGE(1, 1);
        for (int t = 0; t < nt; ++t) {
            if (t + 1 < nt) asm volatile("s_waitcnt vmcnt(6)" ::: "memory");
            else            asm volatile("s_waitcnt vmcnt(0)" ::: "memory");
            __builtin_amdgcn_s_barrier();
            asm volatile("" ::: "memory");

            const u16* buf = smem + (t & 1) * BUFU;
            bf16x8 a_[2][2], b_[4][2];
            #pragma unroll
            for (int i = 0; i < 2; ++i)
                #pragma unroll
                for (int h = 0; h < 2; ++h)
                    a_[i][h] = *reinterpret_cast<const bf16x8*>(&buf[aoff[i][h]]);
            #pragma unroll
            for (int j = 0; j < 4; ++j)
                #pragma unroll
                for (int h = 0; h < 2; ++h)
                    b_[j][h] = *reinterpret_cast<const bf16x8*>(&buf[boff[j][h]]);

            asm volatile("s_waitcnt lgkmcnt(0)" ::: "memory");
            __builtin_amdgcn_s_barrier();
            asm volatile("" ::: "memory");

            if (t + 2 < nt) STAGE(t + 2, t & 1);

            __builtin_amdgcn_s_setprio(1);
            #pragma unroll
            for (int h = 0; h < 2; ++h)
                #pragma unroll
                for (int i = 0; i < 2; ++i)
                    #pragma unroll
                    for (int j = 0; j < 4; ++j) {
                        if (EPI == 4)   // unswapped: reg dim = M (transposed store)
                            acc[i][j] = __builtin_amdgcn_mfma_f32_16x16x32_bf16(
                                a_[i][h], b_[j][h], acc[i][j], 0, 0, 0);
                        else            // swapped: reg dim = N (row-major stores)
                            acc[i][j] = __builtin_amdgcn_mfma_f32_16x16x32_bf16(
                                b_[j][h], a_[i][h], acc[i][j], 0, 0, 0);
                    }
            __builtin_amdgcn_s_setprio(0);
        }
    }

    const int lq = lane >> 4;
    if (EPI == 4) {
        // D[m=lq*4+reg][n=l15]; store u16x4 down vT's contiguous token dim
        #pragma unroll
        for (int j = 0; j < 4; ++j) {
            const int col = n0 + wc + (j << 4) + l15;
            const float bj = bias[col];
            #pragma unroll
            for (int i = 0; i < 2; ++i) {
                const int row0 = m0 + wr + (i << 4) + (lq << 2);
                u16x4 pk;
                #pragma unroll
                for (int r = 0; r < 4; ++r) pk[r] = f2bf(acc[i][j][r] + bj);
                *reinterpret_cast<u16x4*>(&((u16*)C)[(size_t)col * ldc + row0]) = pk;
            }
        }
    } else {
        // swapped: D[n=lq*4+reg][m=l15] -> reg walks C columns (row-major!)
        #pragma unroll
        for (int j = 0; j < 4; ++j) {
            const int col0 = n0 + wc + (j << 4) + (lq << 2);
            float4 bj = {0.f, 0.f, 0.f, 0.f};
            if (EPI != 0) bj = *reinterpret_cast<const float4*>(&bias[col0]);
            #pragma unroll
            for (int i = 0; i < 2; ++i) {
                const int row = m0 + wr + (i << 4) + l15;
                f32x4 v = acc[i][j];
                if (EPI == 0) {
                    v[0] *= scale; v[1] *= scale; v[2] *= scale; v[3] *= scale;
                    *reinterpret_cast<f32x4*>(&((float*)C)[(size_t)row * ldc + col0]) = v;
                } else if (EPI == 1) {
                    v[0] += bj.x; v[1] += bj.y; v[2] += bj.z; v[3] += bj.w;
                    *reinterpret_cast<f32x4*>(&((float*)C)[(size_t)row * ldc + col0]) = v;
                } else {
                    v[0] += bj.x; v[1] += bj.y; v[2] += bj.z; v[3] += bj.w;
                    if (EPI == 3) {
                        v[0] = gelu_f(v[0]); v[1] = gelu_f(v[1]);
                        v[2] = gelu_f(v[2]); v[3] = gelu_f(v[3]);
                    }
                    u16x4 pk = {f2bf(v[0]), f2bf(v[1]), f2bf(v[2]), f2bf(v[3])};
                    *reinterpret_cast<u16x4*>(&((u16*)C)[(size_t)row * ldc + col0]) = pk;
                }
            }
        }
    }
}

template<int EPI>
__global__ __launch_bounds__(256, 3) void mgemm(
    const u16* __restrict__ A, int lda, const u16* __restrict__ B, int ldb,
    const float* __restrict__ bias, void* __restrict__ C, int ldc, int K, float scale)
{
    const int m0 = blockIdx.x << 6;
    const int n0 = blockIdx.y << 7;
    __shared__ u16 smem[2 * BUFU];
    mgemm_body<EPI>(A, lda, B, ldb, bias, C, ldc, 0, K, scale, m0, n0, smem);
}

// block-causal score GEMM: 64-row x 128-col tiles; live iff by <= bx>>1.
__device__ __forceinline__ int tri_pref(int b) {
    const int h = b >> 1;
    return (b & 1) ? (h + 1) * (h + 1) : h * (h + 1);
}
__global__ __launch_bounds__(256, 3) void mgemm_tri(
    const u16* __restrict__ A, const u16* __restrict__ B,
    float* __restrict__ C, float scale)
{
    const int z = blockIdx.x;
    int bx = 2 * (int)sqrtf((float)z);
    while (tri_pref(bx + 1) <= z) ++bx;
    while (tri_pref(bx) > z) --bx;
    const int by = z - tri_pref(bx);
    __shared__ u16 smem[2 * BUFU];
    mgemm_body<0>(A, 512, B, 512, nullptr, C, 4096, 0, 512, scale,
                  bx << 6, by << 7, smem);
}

// split-K partial GEMM: writes raw f32 acc to Cpart + z*RD.
// AVK: K limit = m0+64 (p zero-padded to there), chunk balanced per row-block.
template<bool AVK>
__global__ __launch_bounds__(256, 3) void mgemm_pk(
    const u16* __restrict__ A, int lda, const u16* __restrict__ B, int ldb,
    float* __restrict__ Cpart, int K, int chunk)
{
    const int m0 = blockIdx.x << 6;
    const int n0 = blockIdx.y << 7;
    const int z  = blockIdx.z;
    const int Klim = AVK ? (m0 + 64) : K;
    const int ch = AVK ? ((((Klim >> 2) + 63) >> 6) << 6) : chunk;
    int kBeg = z * ch; if (kBeg > Klim) kBeg = Klim;
    int kEnd = kBeg + ch; if (kEnd > Klim) kEnd = Klim;
    __shared__ u16 smem[2 * BUFU];
    mgemm_body<0>(A, lda, B, ldb, nullptr, Cpart + (size_t)z * RD, 512,
                  kBeg, kEnd, 1.f, m0, n0, smem);
}

// fused QKV: grid.y = which*4 + n_block.  q,k: bf16+bias; v: bf16+bias transposed
__global__ __launch_bounds__(256, 3) void qkv_gemm(
    const u16* __restrict__ xa, const u16* __restrict__ cfb,
    const u16* __restrict__ Wqb, const u16* __restrict__ Wkb, const u16* __restrict__ Wvb,
    const float* __restrict__ bq, const float* __restrict__ bk, const float* __restrict__ bv,
    u16* __restrict__ q, u16* __restrict__ k, u16* __restrict__ vT)
{
    __shared__ u16 smem[2 * BUFU];
    const int m0 = blockIdx.x << 6;
    const int which = blockIdx.y >> 2;
    const int n0 = (blockIdx.y & 3) << 7;
    if (which == 0)
        mgemm_body<2>(xa,  512, Wqb, 512, bq, q,  512,  0, 512, 1.f, m0, n0, smem);
    else if (which == 1)
        mgemm_body<2>(cfb, 512, Wkb, 512, bk, k,  512,  0, 512, 1.f, m0, n0, smem);
    else
        mgemm_body<4>(cfb, 512, Wvb, 512, bv, vT, 4096, 0, 512, 1.f, m0, n0, smem);
}

// ------- masked row softmax (2 passes): p = exp(s - max) bf16 (UNNORMALIZED),
//         sums[row] = sum of exponentials; zero-pads p to the 64-aligned edge.
__global__ __launch_bounds__(256) void softmax_pbf(
    const float* __restrict__ S, u16* __restrict__ P, float* __restrict__ sums)
{
    const int row = blockIdx.x;
    const int b   = row >> 5;
    const int Lb  = b << 5;
    const int bound = ((row >> 6) + 1) << 6;   // AV K bound for this row-block
    const float* s = S + (size_t)row * 4096;
    u16* p = P + (size_t)row * 4096;
    const int tid = threadIdx.x;

    const u16x8 z8 = {0, 0, 0, 0, 0, 0, 0, 0};
    for (int m = Lb + tid * 8; m < bound; m += 2048)
        *reinterpret_cast<u16x8*>(&p[m]) = z8;
    if (b == 0) { if (tid == 0) sums[row] = 1.f; return; }

    __shared__ float red[4];
    float mx = -3.0e38f;
    for (int m = tid * 4; m < Lb; m += 1024) {
        const float4 v = *reinterpret_cast<const float4*>(&s[m]);
        mx = fmaxf(mx, fmaxf(fmaxf(v.x, v.y), fmaxf(v.z, v.w)));
    }
    #pragma unroll
    for (int off = 32; off; off >>= 1) mx = fmaxf(mx, __shfl_xor(mx, off));
    if ((tid & 63) == 0) red[tid >> 6] = mx;
    __syncthreads();
    mx = fmaxf(fmaxf(red[0], red[1]), fmaxf(red[2], red[3]));
    __syncthreads();

    float sum = 0.f;
    for (int m = tid * 8; m < Lb; m += 2048) {
        const float4 v0 = *reinterpret_cast<const float4*>(&s[m]);
        const float4 v1 = *reinterpret_cast<const float4*>(&s[m + 4]);
        float e[8];
        e[0] = expf(v0.x - mx); e[1] = expf(v0.y - mx);
        e[2] = expf(v0.z - mx); e[3] = expf(v0.w - mx);
        e[4] = expf(v1.x - mx); e[5] = expf(v1.y - mx);
        e[6] = expf(v1.z - mx); e[7] = expf(v1.w - mx);
        u16x8 o;
        #pragma unroll
        for (int i = 0; i < 8; ++i) { sum += e[i]; o[i] = f2bf(e[i]); }
        *reinterpret_cast<u16x8*>(&p[m]) = o;
    }
    #pragma unroll
    for (int off = 32; off; off >>= 1) sum += __shfl_xor(sum, off);
    if ((tid & 63) == 0) red[tid >> 6] = sum;
    __syncthreads();
    if (tid == 0)
        sums[row] = fmaxf(red[0] + red[1] + red[2] + red[3], 1e-30f);
}

// --- x = LN(xin + (sum_s part[s]) * (DIV? 1/sums[row] : 1) (+bias)) ---------
template<int NS, bool HASB, bool DIV>
__global__ __launch_bounds__(256) void ln_res_ps(
    const float* __restrict__ Xin, const float* __restrict__ part,
    const float* __restrict__ bias, const float* __restrict__ sums,
    const float* __restrict__ gamma, const float* __restrict__ beta,
    float* __restrict__ Xout, u16* __restrict__ Xbf)
{
    const int row  = blockIdx.x * 4 + (threadIdx.x >> 6);
    const int lane = threadIdx.x & 63;
    const float* xr = Xin + (size_t)row * DIM;
    const int d0 = lane << 3;
    const float inv = DIV ? (1.0f / sums[row]) : 1.0f;

    const float4 x0 = *reinterpret_cast<const float4*>(&xr[d0]);
    const float4 x1 = *reinterpret_cast<const float4*>(&xr[d0 + 4]);
    float a[8] = {0.f, 0.f, 0.f, 0.f, 0.f, 0.f, 0.f, 0.f};
    #pragma unroll
    for (int s = 0; s < NS; ++s) {
        const float* pr = part + (size_t)s * RD + (size_t)row * DIM + d0;
        const float4 p0 = *reinterpret_cast<const float4*>(pr);
        const float4 p1 = *reinterpret_cast<const float4*>(pr + 4);
        a[0] += p0.x; a[1] += p0.y; a[2] += p0.z; a[3] += p0.w;
        a[4] += p1.x; a[5] += p1.y; a[6] += p1.z; a[7] += p1.w;
    }
    float v[8] = {x0.x, x0.y, x0.z, x0.w, x1.x, x1.y, x1.z, x1.w};
    #pragma unroll
    for (int i = 0; i < 8; ++i) v[i] += a[i] * inv;
    if (HASB) {
        const float4 b0 = *reinterpret_cast<const float4*>(&bias[d0]);
        const float4 b1 = *reinterpret_cast<const float4*>(&bias[d0 + 4]);
        v[0] += b0.x; v[1] += b0.y; v[2] += b0.z; v[3] += b0.w;
        v[4] += b1.x; v[5] += b1.y; v[6] += b1.z; v[7] += b1.w;
    }

    float sm = 0.f;
    #pragma unroll
    for (int i = 0; i < 8; ++i) sm += v[i];
    #pragma unroll
    for (int off = 32; off; off >>= 1) sm += __shfl_xor(sm, off);
    const float mu = sm * (1.0f / 512.0f);

    float qs = 0.f;
    #pragma unroll
    for (int i = 0; i < 8; ++i) { const float d = v[i] - mu; qs += d * d; }
    #pragma unroll
    for (int off = 32; off; off >>= 1) qs += __shfl_xor(qs, off);
    const float rs = rsqrtf(qs * (1.0f / 512.0f) + 1e-5f);

    const float4 g0 = *reinterpret_cast<const float4*>(&gamma[d0]);
    const float4 g1 = *reinterpret_cast<const float4*>(&gamma[d0 + 4]);
    const float4 b0 = *reinterpret_cast<const float4*>(&beta[d0]);
    const float4 b1 = *reinterpret_cast<const float4*>(&beta[d0 + 4]);
    float o[8];
    o[0] = (v[0] - mu) * rs * g0.x + b0.x;
    o[1] = (v[1] - mu) * rs * g0.y + b0.y;
    o[2] = (v[2] - mu) * rs * g0.z + b0.z;
    o[3] = (v[3] - mu) * rs * g0.w + b0.w;
    o[4] = (v[4] - mu) * rs * g1.x + b1.x;
    o[5] = (v[5] - mu) * rs * g1.y + b1.y;
    o[6] = (v[6] - mu) * rs * g1.z + b1.z;
    o[7] = (v[7] - mu) * rs * g1.w + b1.w;

    float4 f0 = {o[0], o[1], o[2], o[3]}, f1 = {o[4], o[5], o[6], o[7]};
    *reinterpret_cast<float4*>(&Xout[(size_t)row * DIM + d0])     = f0;
    *reinterpret_cast<float4*>(&Xout[(size_t)row * DIM + d0 + 4]) = f1;
    u16x8 ob;
    #pragma unroll
    for (int i = 0; i < 8; ++i) ob[i] = f2bf(o[i]);
    *reinterpret_cast<u16x8*>(&Xbf[(size_t)row * DIM + d0]) = ob;
}

// ---------------- fused f32->bf16 conversion for 7 arrays -------------------
struct ConvArgs {
    const float* src[7];
    u16* dst[7];
    int start[8];
};

__global__ __launch_bounds__(256) void conv_all(ConvArgs a)
{
    const int b = blockIdx.x;
    int seg = 0;
    #pragma unroll
    for (int i = 1; i < 7; ++i) seg += (a.start[i] <= b) ? 1 : 0;
    const int i = ((b - a.start[seg]) * 256 + threadIdx.x) << 3;
    const float* s = a.src[seg];
    const float4 lo = *reinterpret_cast<const float4*>(&s[i]);
    const float4 hi = *reinterpret_cast<const float4*>(&s[i + 4]);
    u16x8 o = {f2bf(lo.x), f2bf(lo.y), f2bf(lo.z), f2bf(lo.w),
               f2bf(hi.x), f2bf(hi.y), f2bf(hi.z), f2bf(hi.w)};
    *reinterpret_cast<u16x8*>(&a.dst[seg][i]) = o;
}

// ---------------- small helpers ---------------------------------------------
__global__ __launch_bounds__(256) void build_cat(
    u16* __restrict__ cat, const u16* __restrict__ cfb, const u16* __restrict__ xbf)
{
    const int idx = blockIdx.x * 256 + threadIdx.x;
    const int row = idx >> 7;
    const int c8  = idx & 127;
    const u16* src2 = (row < 32) ? cfb : xbf;
    const u16x8 v = (c8 < 64)
        ? *reinterpret_cast<const u16x8*>(&cfb[(size_t)row * 512 + (c8 << 3)])
        : *reinterpret_cast<const u16x8*>(&src2[(size_t)row * 512 + ((c8 - 64) << 3)]);
    *reinterpret_cast<u16x8*>(&cat[(size_t)row * 1024 + (c8 << 3)]) = v;
}

__global__ __launch_bounds__(256) void final_gate_ps(
    float4* __restrict__ out, const float4* __restrict__ cf,
    const float4* __restrict__ x, const float* __restrict__ part,
    const float* __restrict__ bias)
{
    const int idx = blockIdx.x * 256 + threadIdx.x;
    const int row = idx >> 7;
    const int c4  = idx & 127;
    const float4 zc = cf[idx];
    const float4 p0 = reinterpret_cast<const float4*>(part)[idx];
    const float4 p1 = reinterpret_cast<const float4*>(part + RD)[idx];
    const float4 bb = *reinterpret_cast<const float4*>(&bias[c4 << 2]);
    const float4 za = (row < 32) ? zc : x[idx];
    float4 o;
    { const float g = 1.0f / (1.0f + expf(-(p0.x + p1.x + bb.x))); o.x = g * zc.x + (1.0f - g) * za.x; }
    { const float g = 1.0f / (1.0f + expf(-(p0.y + p1.y + bb.y))); o.y = g * zc.y + (1.0f - g) * za.y; }
    { const float g = 1.0f / (1.0f + expf(-(p0.z + p1.z + bb.z))); o.z = g * zc.z + (1.0f - g) * za.z; }
    { const float g = 1.0f / (1.0f + expf(-(p0.w + p1.w + bb.w))); o.w = g * zc.w + (1.0f - g) * za.w; }
    out[idx] = o;
}

// ---------------------------------------------------------------------------
extern "C" void kernel_launch(void* const* d_in, const int* in_sizes, int n_in,
                              void* d_out, int out_size, void* d_ws, size_t ws_size,
                              hipStream_t stream)
{
    const float* cf   = (const float*)d_in[0];
    const float* Wq   = (const float*)d_in[1];
    const float* bq   = (const float*)d_in[2];
    const float* Wk   = (const float*)d_in[3];
    const float* bk   = (const float*)d_in[4];
    const float* Wv   = (const float*)d_in[5];
    const float* bv   = (const float*)d_in[6];
    const float* ln1g = (const float*)d_in[7];
    const float* ln1b = (const float*)d_in[8];
    const float* W1   = (const float*)d_in[9];
    const float* b1   = (const float*)d_in[10];
    const float* W2   = (const float*)d_in[11];
    const float* b2   = (const float*)d_in[12];
    const float* ln2g = (const float*)d_in[13];
    const float* ln2b = (const float*)d_in[14];
    const float* Wsg  = (const float*)d_in[15];
    const float* bsg  = (const float*)d_in[16];
    float* out = (float*)d_out;

    float* ws   = (float*)d_ws;
    float* x    = ws;                               // [4096,512] f32
    float* sums = ws + RD;                          // [4096] f32
    float* s    = ws + 2 * RD;                      // [4096,4096] f32 (attn)
    float* part = ws + 2 * RD;                      // 4x[4096,512] f32 partials
                                                    // (aliases s; s dead then)
    u16*  pbf  = (u16*)(ws + 10 * RD);              // shared: p / h / cat (bf16)
    u16*  hbf  = pbf;
    u16*  catb = pbf;
    u16*  bfb  = (u16*)(ws + 14 * RD);
    u16* cfb = bfb;
    u16* xbf = bfb + RD;
    u16* qbf = bfb + 2 * RD;
    u16* kbf = bfb + 3 * RD;
    u16* vTb = bfb + 4 * RD;                        // [512,4096] (V transposed)
    u16* Wqb = bfb + 5 * RD;
    u16* Wkb = Wqb + 524288;
    u16* Wvb = Wkb + 524288;
    u16* W1b = Wvb + 524288;
    u16* W2b = W1b + 2097152;
    u16* Wsb = W2b + 2097152;

    const float scale = 0.044194173824159216f;      // 1/sqrt(512)

    ConvArgs ca;
    ca.src[0] = cf;  ca.dst[0] = cfb;
    ca.src[1] = Wq;  ca.dst[1] = Wqb;
    ca.src[2] = Wk;  ca.dst[2] = Wkb;
    ca.src[3] = Wv;  ca.dst[3] = Wvb;
    ca.src[4] = W1;  ca.dst[4] = W1b;
    ca.src[5] = W2;  ca.dst[5] = W2b;
    ca.src[6] = Wsg; ca.dst[6] = Wsb;
    ca.start[0] = 0;    ca.start[1] = 1024; ca.start[2] = 1280;
    ca.start[3] = 1536; ca.start[4] = 1792; ca.start[5] = 2816;
    ca.start[6] = 3840; ca.start[7] = 4096;
    conv_all<<<4096, 256, 0, stream>>>(ca);

    for (int l = 0; l < 2; ++l) {
        const u16* xa = (l == 0) ? cfb : xbf;
        qkv_gemm<<<dim3(64, 12), 256, 0, stream>>>(
            xa, cfb, Wqb + l * 262144, Wkb + l * 262144, Wvb + l * 262144,
            bq + l * 512, bk + l * 512, bv + l * 512, qbf, kbf, vTb);
        mgemm_tri<<<1056, 256, 0, stream>>>(qbf, kbf, s, scale);
        softmax_pbf<<<4096, 256, 0, stream>>>(s, pbf, sums);
        // AV: split-K 4, balanced per row-block (s region dead -> partials alias)
        mgemm_pk<true><<<dim3(64, 4, 4), 256, 0, stream>>>(
            pbf, 4096, vTb, 4096, part, 4096, 0);
        ln_res_ps<4, false, true><<<1024, 256, 0, stream>>>(
            (l == 0) ? cf : x, part, nullptr, sums,
            ln1g + l * 512, ln1b + l * 512, x, xbf);
        mgemm<3><<<dim3(64, 16), 256, 0, stream>>>(
            xbf, 512, W1b + l * 1048576, 512, b1 + l * 2048, hbf, 2048, 512, 1.f);
        // MLP2: split-K 4 x 512
        mgemm_pk<false><<<dim3(64, 4, 4), 256, 0, stream>>>(
            hbf, 2048, W2b + l * 1048576, 2048, part, 2048, 512);
        ln_res_ps<4, true, false><<<1024, 256, 0, stream>>>(
            x, part, b2 + l * 512, nullptr,
            ln2g + l * 512, ln2b + l * 512, x, xbf);
    }

    build_cat<<<2048, 256, 0, stream>>>(catb, cfb, xbf);
    // gate: split-K 2 x 512
    mgemm_pk<false><<<dim3(64, 4, 2), 256, 0, stream>>>(
        catb, 1024, Wsb, 1024, part, 1024, 512);
    final_gate_ps<<<2048, 256, 0, stream>>>((float4*)out, (const float4*)cf,
                                            (const float4*)x, part, bsg);
}

// Round 7
// 271.131 us; speedup vs baseline: 6.3891x; 1.0003x over previous
//
#include <hip/hip_runtime.h>
#include <cmath>

// ---------------------------------------------------------------------------
// MemoryBankV2: B=128, T=32, D=512, L=2.  Rows = B*T = 4096.
// Round 7: BM templated (128 for big GEMMs, 64 for QKV), BK=64 two-barrier
// phase with counted vmcnt(NL), swapped-operand MFMA vectorized epilogues,
// 2-pass softmax with normalization fused into ln_res.
// ---------------------------------------------------------------------------

#define ROWS 4096
#define DIM  512

typedef __bf16 bf16x8 __attribute__((ext_vector_type(8)));
typedef float  f32x4  __attribute__((ext_vector_type(4)));
typedef unsigned short u16;
typedef u16 u16x4 __attribute__((ext_vector_type(4)));
typedef u16 u16x8 __attribute__((ext_vector_type(8)));

#define RD ((size_t)ROWS * DIM)

__device__ __forceinline__ u16 f2bf(float x) {
    union { float f; unsigned u; } c; c.f = x;
    const unsigned r = (c.u + 0x7FFFu + ((c.u >> 16) & 1u)) >> 16;
    return (u16)r;
}

__device__ __forceinline__ void gload16(const void* g, void* l) {
    __builtin_amdgcn_global_load_lds(
        (const __attribute__((address_space(1))) void*)g,
        (__attribute__((address_space(3))) void*)l, 16, 0, 0);
}

__device__ __forceinline__ float gelu_f(float v) {
    return 0.5f * v * (1.0f + erff(v * 0.70710678118654752f));
}

// ---------------- MFMA GEMM body --------------------------------------------
// C[M,N] = epi(A[M,K] @ B[N,K]^T), K range [kBeg,kEnd), BMx128 tile, BK=64.
// LDS 16B-slot layout: slot(row, subp); stored sub-chunk = subp ^ (row&7)
// (XOR swizzle; conflict-free ds_read_b128 frag reads; write side is
// linear for global_load_lds with pre-swizzled global source).
// Two-barrier phase per K-step, counted vmcnt(NL): one stage spans barriers.
// EPI: 0: f32 = acc*scale | 1: f32 = acc+bias | 2: bf16 = acc+bias
//      3: bf16 = gelu(acc+bias) | 4: bf16 transposed (C[col*ldc+row]) = acc+bias
template<int EPI, int BM>
__device__ __forceinline__ void mgemm_body(
    const u16* __restrict__ A, int lda,
    const u16* __restrict__ B, int ldb,
    const float* __restrict__ bias,
    void* __restrict__ C, int ldc,
    int kBeg, int kEnd, float scale, int m0, int n0, u16* smem)
{
    constexpr int RI  = BM / 32;         // row frags per wave (2 or 4)
    constexpr int AQ  = BM / 32;         // A stage chunks per wave
    constexpr int AU  = BM * 64;         // A region size (u16)
    constexpr int BUF = (BM + 128) * 64; // buffer size (u16)
    constexpr int NL  = AQ + 4;          // gloads per thread per stage

    const int tid  = threadIdx.x;
    const int lane = tid & 63;
    const int w    = tid >> 6;           // wave 0..3 (2x2 over BMx128 tile)
    const int wr   = (w >> 1) * (BM / 2);
    const int wc   = (w & 1) << 6;

    f32x4 acc[RI][4];
    #pragma unroll
    for (int i = 0; i < RI; ++i)
        #pragma unroll
        for (int j = 0; j < 4; ++j)
            acc[i][j] = (f32x4){0.f, 0.f, 0.f, 0.f};

    // ---- staging map: chunks of 64 slots; wave w owns chunks q*4+w ----
    const u16* gpA[AQ]; int loA[AQ];
    #pragma unroll
    for (int q = 0; q < AQ; ++q) {
        const int c = (q << 2) + w;
        const int s = (c << 6) + lane;
        const int row = s >> 3, sub = (s & 7) ^ (row & 7);
        gpA[q] = A + (size_t)(m0 + row) * lda + (sub << 3) + kBeg;
        loA[q] = c << 9;
    }
    const u16* gpB[4]; int loB[4];
    #pragma unroll
    for (int q = 0; q < 4; ++q) {
        const int c = (q << 2) + w;
        const int s = (c << 6) + lane;
        const int row = s >> 3, sub = (s & 7) ^ (row & 7);
        gpB[q] = B + (size_t)(n0 + row) * ldb + (sub << 3) + kBeg;
        loB[q] = AU + (c << 9);
    }

    // ---- fragment LDS offsets (u16 units, within buffer) ----
    const int l15 = lane & 15, kg = lane >> 4;
    int aoff[RI][2], boff[4][2];
    #pragma unroll
    for (int i = 0; i < RI; ++i)
        #pragma unroll
        for (int h = 0; h < 2; ++h) {
            const int r = wr + (i << 4) + l15;
            const int sub = ((h << 2) + kg) ^ (r & 7);
            aoff[i][h] = ((r << 3) + sub) << 3;
        }
    #pragma unroll
    for (int j = 0; j < 4; ++j)
        #pragma unroll
        for (int h = 0; h < 2; ++h) {
            const int r = wc + (j << 4) + l15;
            const int sub = ((h << 2) + kg) ^ (r & 7);
            boff[j][h] = AU + (((r << 3) + sub) << 3);
        }

    const int nt = (kEnd - kBeg) >> 6;

    auto STAGE = [&](int t, int bsel) {
        u16* base = smem + bsel * BUF;
        const int ko = t << 6;
        #pragma unroll
        for (int q = 0; q < AQ; ++q) gload16(gpA[q] + ko, base + loA[q]);
        #pragma unroll
        for (int q = 0; q < 4; ++q)  gload16(gpB[q] + ko, base + loB[q]);
    };

    if (nt > 0) {
        STAGE(0, 0);
        if (nt > 1) STAGE(1, 1);
        for (int t = 0; t < nt; ++t) {
            if (t + 1 < nt) {
                if constexpr (NL == 8) asm volatile("s_waitcnt vmcnt(8)" ::: "memory");
                else                   asm volatile("s_waitcnt vmcnt(6)" ::: "memory");
            } else {
                asm volatile("s_waitcnt vmcnt(0)" ::: "memory");
            }
            __builtin_amdgcn_s_barrier();
            asm volatile("" ::: "memory");

            const u16* buf = smem + (t & 1) * BUF;
            bf16x8 a_[RI][2], b_[4][2];
            #pragma unroll
            for (int i = 0; i < RI; ++i)
                #pragma unroll
                for (int h = 0; h < 2; ++h)
                    a_[i][h] = *reinterpret_cast<const bf16x8*>(&buf[aoff[i][h]]);
            #pragma unroll
            for (int j = 0; j < 4; ++j)
                #pragma unroll
                for (int h = 0; h < 2; ++h)
                    b_[j][h] = *reinterpret_cast<const bf16x8*>(&buf[boff[j][h]]);

            asm volatile("s_waitcnt lgkmcnt(0)" ::: "memory");
            __builtin_amdgcn_s_barrier();
            asm volatile("" ::: "memory");

            if (t + 2 < nt) STAGE(t + 2, t & 1);

            __builtin_amdgcn_s_setprio(1);
            #pragma unroll
            for (int h = 0; h < 2; ++h)
                #pragma unroll
                for (int i = 0; i < RI; ++i)
                    #pragma unroll
                    for (int j = 0; j < 4; ++j) {
                        if (EPI == 4)   // unswapped: reg dim = M (transposed store)
                            acc[i][j] = __builtin_amdgcn_mfma_f32_16x16x32_bf16(
                                a_[i][h], b_[j][h], acc[i][j], 0, 0, 0);
                        else            // swapped: reg dim = N (row-major stores)
                            acc[i][j] = __builtin_amdgcn_mfma_f32_16x16x32_bf16(
                                b_[j][h], a_[i][h], acc[i][j], 0, 0, 0);
                    }
            __builtin_amdgcn_s_setprio(0);
        }
    }

    const int lq = lane >> 4;
    if (EPI == 4) {
        // D[m=lq*4+reg][n=l15]; store u16x4 down vT's contiguous token dim
        #pragma unroll
        for (int j = 0; j < 4; ++j) {
            const int col = n0 + wc + (j << 4) + l15;
            const float bj = bias[col];
            #pragma unroll
            for (int i = 0; i < RI; ++i) {
                const int row0 = m0 + wr + (i << 4) + (lq << 2);
                u16x4 pk;
                #pragma unroll
                for (int r = 0; r < 4; ++r) pk[r] = f2bf(acc[i][j][r] + bj);
                *reinterpret_cast<u16x4*>(&((u16*)C)[(size_t)col * ldc + row0]) = pk;
            }
        }
    } else {
        // swapped: D[n=lq*4+reg][m=l15] -> reg walks C columns (row-major!)
        #pragma unroll
        for (int j = 0; j < 4; ++j) {
            const int col0 = n0 + wc + (j << 4) + (lq << 2);
            float4 bj = {0.f, 0.f, 0.f, 0.f};
            if (EPI != 0) bj = *reinterpret_cast<const float4*>(&bias[col0]);
            #pragma unroll
            for (int i = 0; i < RI; ++i) {
                const int row = m0 + wr + (i << 4) + l15;
                f32x4 v = acc[i][j];
                if (EPI == 0) {
                    v[0] *= scale; v[1] *= scale; v[2] *= scale; v[3] *= scale;
                    *reinterpret_cast<f32x4*>(&((float*)C)[(size_t)row * ldc + col0]) = v;
                } else if (EPI == 1) {
                    v[0] += bj.x; v[1] += bj.y; v[2] += bj.z; v[3] += bj.w;
                    *reinterpret_cast<f32x4*>(&((float*)C)[(size_t)row * ldc + col0]) = v;
                } else {
                    v[0] += bj.x; v[1] += bj.y; v[2] += bj.z; v[3] += bj.w;
                    if (EPI == 3) {
                        v[0] = gelu_f(v[0]); v[1] = gelu_f(v[1]);
                        v[2] = gelu_f(v[2]); v[3] = gelu_f(v[3]);
                    }
                    u16x4 pk = {f2bf(v[0]), f2bf(v[1]), f2bf(v[2]), f2bf(v[3])};
                    *reinterpret_cast<u16x4*>(&((u16*)C)[(size_t)row * ldc + col0]) = pk;
                }
            }
        }
    }
}

template<int EPI>
__global__ __launch_bounds__(256, 2) void mgemm(
    const u16* __restrict__ A, int lda, const u16* __restrict__ B, int ldb,
    const float* __restrict__ bias, void* __restrict__ C, int ldc, int K, float scale)
{
    const int m0 = blockIdx.x << 7;
    const int n0 = blockIdx.y << 7;
    __shared__ u16 smem[2 * 256 * 64];
    mgemm_body<EPI, 128>(A, lda, B, ldb, bias, C, ldc, 0, K, scale, m0, n0, smem);
}

// block-causal score GEMM: 128x128 tiles; live iff 128*by < 128*bx+96, i.e.
// by <= bx.  Triangular grid of 528 blocks.
__global__ __launch_bounds__(256, 2) void mgemm_tri(
    const u16* __restrict__ A, const u16* __restrict__ B,
    float* __restrict__ C, float scale)
{
    const int z = blockIdx.x;
    int bx = (int)((sqrtf((float)(8 * z + 1)) - 1.0f) * 0.5f);
    while ((bx + 1) * (bx + 2) / 2 <= z) ++bx;
    while (bx * (bx + 1) / 2 > z) --bx;
    const int by = z - bx * (bx + 1) / 2;
    __shared__ u16 smem[2 * 256 * 64];
    mgemm_body<0, 128>(A, 512, B, 512, nullptr, C, 4096, 0, 512, scale,
                       bx << 7, by << 7, smem);
}

// split-K partial GEMM: writes raw f32 acc to Cpart + z*RD.
// AVK: K limit = m0+128 (p zero-padded to there), chunk balanced per row-block.
template<bool AVK>
__global__ __launch_bounds__(256, 2) void mgemm_pk(
    const u16* __restrict__ A, int lda, const u16* __restrict__ B, int ldb,
    float* __restrict__ Cpart, int K, int chunk)
{
    const int m0 = blockIdx.x << 7;
    const int n0 = blockIdx.y << 7;
    const int z  = blockIdx.z;
    const int Klim = AVK ? (m0 + 128) : K;
    const int ch = AVK ? ((((Klim >> 2) + 63) >> 6) << 6) : chunk;
    int kBeg = z * ch; if (kBeg > Klim) kBeg = Klim;
    int kEnd = kBeg + ch; if (kEnd > Klim) kEnd = Klim;
    __shared__ u16 smem[2 * 256 * 64];
    mgemm_body<0, 128>(A, lda, B, ldb, nullptr, Cpart + (size_t)z * RD, 512,
                       kBeg, kEnd, 1.f, m0, n0, smem);
}

// fused QKV (BM=64): grid.y = which*4 + n_block.
__global__ __launch_bounds__(256, 3) void qkv_gemm(
    const u16* __restrict__ xa, const u16* __restrict__ cfb,
    const u16* __restrict__ Wqb, const u16* __restrict__ Wkb, const u16* __restrict__ Wvb,
    const float* __restrict__ bq, const float* __restrict__ bk, const float* __restrict__ bv,
    u16* __restrict__ q, u16* __restrict__ k, u16* __restrict__ vT)
{
    __shared__ u16 smem[2 * 192 * 64];
    const int m0 = blockIdx.x << 6;
    const int which = blockIdx.y >> 2;
    const int n0 = (blockIdx.y & 3) << 7;
    if (which == 0)
        mgemm_body<2, 64>(xa,  512, Wqb, 512, bq, q,  512,  0, 512, 1.f, m0, n0, smem);
    else if (which == 1)
        mgemm_body<2, 64>(cfb, 512, Wkb, 512, bk, k,  512,  0, 512, 1.f, m0, n0, smem);
    else
        mgemm_body<4, 64>(cfb, 512, Wvb, 512, bv, vT, 4096, 0, 512, 1.f, m0, n0, smem);
}

// ------- masked row softmax (2 passes): p = exp(s - max) bf16 (UNNORMALIZED),
//         sums[row] = sum of exponentials; zero-pads p to the 128-aligned edge.
__global__ __launch_bounds__(256) void softmax_pbf(
    const float* __restrict__ S, u16* __restrict__ P, float* __restrict__ sums)
{
    const int row = blockIdx.x;
    const int b   = row >> 5;
    const int Lb  = b << 5;
    const int bound = ((row >> 7) + 1) << 7;   // AV K bound for this row-block
    const float* s = S + (size_t)row * 4096;
    u16* p = P + (size_t)row * 4096;
    const int tid = threadIdx.x;

    const u16x8 z8 = {0, 0, 0, 0, 0, 0, 0, 0};
    for (int m = Lb + tid * 8; m < bound; m += 2048)
        *reinterpret_cast<u16x8*>(&p[m]) = z8;
    if (b == 0) { if (tid == 0) sums[row] = 1.f; return; }

    __shared__ float red[4];
    float mx = -3.0e38f;
    for (int m = tid * 4; m < Lb; m += 1024) {
        const float4 v = *reinterpret_cast<const float4*>(&s[m]);
        mx = fmaxf(mx, fmaxf(fmaxf(v.x, v.y), fmaxf(v.z, v.w)));
    }
    #pragma unroll
    for (int off = 32; off; off >>= 1) mx = fmaxf(mx, __shfl_xor(mx, off));
    if ((tid & 63) == 0) red[tid >> 6] = mx;
    __syncthreads();
    mx = fmaxf(fmaxf(red[0], red[1]), fmaxf(red[2], red[3]));
    __syncthreads();

    float sum = 0.f;
    for (int m = tid * 8; m < Lb; m += 2048) {
        const float4 v0 = *reinterpret_cast<const float4*>(&s[m]);
        const float4 v1 = *reinterpret_cast<const float4*>(&s[m + 4]);
        float e[8];
        e[0] = expf(v0.x - mx); e[1] = expf(v0.y - mx);
        e[2] = expf(v0.z - mx); e[3] = expf(v0.w - mx);
        e[4] = expf(v1.x - mx); e[5] = expf(v1.y - mx);
        e[6] = expf(v1.z - mx); e[7] = expf(v1.w - mx);
        u16x8 o;
        #pragma unroll
        for (int i = 0; i < 8; ++i) { sum += e[i]; o[i] = f2bf(e[i]); }
        *reinterpret_cast<u16x8*>(&p[m]) = o;
    }
    #pragma unroll
    for (int off = 32; off; off >>= 1) sum += __shfl_xor(sum, off);
    if ((tid & 63) == 0) red[tid >> 6] = sum;
    __syncthreads();
    if (tid == 0)
        sums[row] = fmaxf(red[0] + red[1] + red[2] + red[3], 1e-30f);
}

// --- x = LN(xin + (sum_s part[s]) * (DIV? 1/sums[row] : 1) (+bias)) ---------
template<int NS, bool HASB, bool DIV>
__global__ __launch_bounds__(256) void ln_res_ps(
    const float* __restrict__ Xin, const float* __restrict__ part,
    const float* __restrict__ bias, const float* __restrict__ sums,
    const float* __restrict__ gamma, const float* __restrict__ beta,
    float* __restrict__ Xout, u16* __restrict__ Xbf)
{
    const int row  = blockIdx.x * 4 + (threadIdx.x >> 6);
    const int lane = threadIdx.x & 63;
    const float* xr = Xin + (size_t)row * DIM;
    const int d0 = lane << 3;
    const float inv = DIV ? (1.0f / sums[row]) : 1.0f;

    const float4 x0 = *reinterpret_cast<const float4*>(&xr[d0]);
    const float4 x1 = *reinterpret_cast<const float4*>(&xr[d0 + 4]);
    float a[8] = {0.f, 0.f, 0.f, 0.f, 0.f, 0.f, 0.f, 0.f};
    #pragma unroll
    for (int s = 0; s < NS; ++s) {
        const float* pr = part + (size_t)s * RD + (size_t)row * DIM + d0;
        const float4 p0 = *reinterpret_cast<const float4*>(pr);
        const float4 p1 = *reinterpret_cast<const float4*>(pr + 4);
        a[0] += p0.x; a[1] += p0.y; a[2] += p0.z; a[3] += p0.w;
        a[4] += p1.x; a[5] += p1.y; a[6] += p1.z; a[7] += p1.w;
    }
    float v[8] = {x0.x, x0.y, x0.z, x0.w, x1.x, x1.y, x1.z, x1.w};
    #pragma unroll
    for (int i = 0; i < 8; ++i) v[i] += a[i] * inv;
    if (HASB) {
        const float4 b0 = *reinterpret_cast<const float4*>(&bias[d0]);
        const float4 b1 = *reinterpret_cast<const float4*>(&bias[d0 + 4]);
        v[0] += b0.x; v[1] += b0.y; v[2] += b0.z; v[3] += b0.w;
        v[4] += b1.x; v[5] += b1.y; v[6] += b1.z; v[7] += b1.w;
    }

    float sm = 0.f;
    #pragma unroll
    for (int i = 0; i < 8; ++i) sm += v[i];
    #pragma unroll
    for (int off = 32; off; off >>= 1) sm += __shfl_xor(sm, off);
    const float mu = sm * (1.0f / 512.0f);

    float qs = 0.f;
    #pragma unroll
    for (int i = 0; i < 8; ++i) { const float d = v[i] - mu; qs += d * d; }
    #pragma unroll
    for (int off = 32; off; off >>= 1) qs += __shfl_xor(qs, off);
    const float rs = rsqrtf(qs * (1.0f / 512.0f) + 1e-5f);

    const float4 g0 = *reinterpret_cast<const float4*>(&gamma[d0]);
    const float4 g1 = *reinterpret_cast<const float4*>(&gamma[d0 + 4]);
    const float4 b0 = *reinterpret_cast<const float4*>(&beta[d0]);
    const float4 b1 = *reinterpret_cast<const float4*>(&beta[d0 + 4]);
    float o[8];
    o[0] = (v[0] - mu) * rs * g0.x + b0.x;
    o[1] = (v[1] - mu) * rs * g0.y + b0.y;
    o[2] = (v[2] - mu) * rs * g0.z + b0.z;
    o[3] = (v[3] - mu) * rs * g0.w + b0.w;
    o[4] = (v[4] - mu) * rs * g1.x + b1.x;
    o[5] = (v[5] - mu) * rs * g1.y + b1.y;
    o[6] = (v[6] - mu) * rs * g1.z + b1.z;
    o[7] = (v[7] - mu) * rs * g1.w + b1.w;

    float4 f0 = {o[0], o[1], o[2], o[3]}, f1 = {o[4], o[5], o[6], o[7]};
    *reinterpret_cast<float4*>(&Xout[(size_t)row * DIM + d0])     = f0;
    *reinterpret_cast<float4*>(&Xout[(size_t)row * DIM + d0 + 4]) = f1;
    u16x8 ob;
    #pragma unroll
    for (int i = 0; i < 8; ++i) ob[i] = f2bf(o[i]);
    *reinterpret_cast<u16x8*>(&Xbf[(size_t)row * DIM + d0]) = ob;
}

// ---------------- fused f32->bf16 conversion for 7 arrays -------------------
struct ConvArgs {
    const float* src[7];
    u16* dst[7];
    int start[8];
};

__global__ __launch_bounds__(256) void conv_all(ConvArgs a)
{
    const int b = blockIdx.x;
    int seg = 0;
    #pragma unroll
    for (int i = 1; i < 7; ++i) seg += (a.start[i] <= b) ? 1 : 0;
    const int i = ((b - a.start[seg]) * 256 + threadIdx.x) << 3;
    const float* s = a.src[seg];
    const float4 lo = *reinterpret_cast<const float4*>(&s[i]);
    const float4 hi = *reinterpret_cast<const float4*>(&s[i + 4]);
    u16x8 o = {f2bf(lo.x), f2bf(lo.y), f2bf(lo.z), f2bf(lo.w),
               f2bf(hi.x), f2bf(hi.y), f2bf(hi.z), f2bf(hi.w)};
    *reinterpret_cast<u16x8*>(&a.dst[seg][i]) = o;
}

// ---------------- small helpers ---------------------------------------------
__global__ __launch_bounds__(256) void build_cat(
    u16* __restrict__ cat, const u16* __restrict__ cfb, const u16* __restrict__ xbf)
{
    const int idx = blockIdx.x * 256 + threadIdx.x;
    const int row = idx >> 7;
    const int c8  = idx & 127;
    const u16* src2 = (row < 32) ? cfb : xbf;
    const u16x8 v = (c8 < 64)
        ? *reinterpret_cast<const u16x8*>(&cfb[(size_t)row * 512 + (c8 << 3)])
        : *reinterpret_cast<const u16x8*>(&src2[(size_t)row * 512 + ((c8 - 64) << 3)]);
    *reinterpret_cast<u16x8*>(&cat[(size_t)row * 1024 + (c8 << 3)]) = v;
}

__global__ __launch_bounds__(256) void final_gate_ps(
    float4* __restrict__ out, const float4* __restrict__ cf,
    const float4* __restrict__ x, const float* __restrict__ part,
    const float* __restrict__ bias)
{
    const int idx = blockIdx.x * 256 + threadIdx.x;
    const int row = idx >> 7;
    const int c4  = idx & 127;
    const float4 zc = cf[idx];
    const float4 p0 = reinterpret_cast<const float4*>(part)[idx];
    const float4 p1 = reinterpret_cast<const float4*>(part + RD)[idx];
    const float4 bb = *reinterpret_cast<const float4*>(&bias[c4 << 2]);
    const float4 za = (row < 32) ? zc : x[idx];
    float4 o;
    { const float g = 1.0f / (1.0f + expf(-(p0.x + p1.x + bb.x))); o.x = g * zc.x + (1.0f - g) * za.x; }
    { const float g = 1.0f / (1.0f + expf(-(p0.y + p1.y + bb.y))); o.y = g * zc.y + (1.0f - g) * za.y; }
    { const float g = 1.0f / (1.0f + expf(-(p0.z + p1.z + bb.z))); o.z = g * zc.z + (1.0f - g) * za.z; }
    { const float g = 1.0f / (1.0f + expf(-(p0.w + p1.w + bb.w))); o.w = g * zc.w + (1.0f - g) * za.w; }
    out[idx] = o;
}

// ---------------------------------------------------------------------------
extern "C" void kernel_launch(void* const* d_in, const int* in_sizes, int n_in,
                              void* d_out, int out_size, void* d_ws, size_t ws_size,
                              hipStream_t stream)
{
    const float* cf   = (const float*)d_in[0];
    const float* Wq   = (const float*)d_in[1];
    const float* bq   = (const float*)d_in[2];
    const float* Wk   = (const float*)d_in[3];
    const float* bk   = (const float*)d_in[4];
    const float* Wv   = (const float*)d_in[5];
    const float* bv   = (const float*)d_in[6];
    const float* ln1g = (const float*)d_in[7];
    const float* ln1b = (const float*)d_in[8];
    const float* W1   = (const float*)d_in[9];
    const float* b1   = (const float*)d_in[10];
    const float* W2   = (const float*)d_in[11];
    const float* b2   = (const float*)d_in[12];
    const float* ln2g = (const float*)d_in[13];
    const float* ln2b = (const float*)d_in[14];
    const float* Wsg  = (const float*)d_in[15];
    const float* bsg  = (const float*)d_in[16];
    float* out = (float*)d_out;

    float* ws   = (float*)d_ws;
    float* x    = ws;                               // [4096,512] f32
    float* sums = ws + RD;                          // [4096] f32
    float* s    = ws + 2 * RD;                      // [4096,4096] f32 (attn)
    float* part = ws + 2 * RD;                      // 4x[4096,512] f32 partials
                                                    // (aliases s; s dead then)
    u16*  pbf  = (u16*)(ws + 10 * RD);              // shared: p / h / cat (bf16)
    u16*  hbf  = pbf;
    u16*  catb = pbf;
    u16*  bfb  = (u16*)(ws + 14 * RD);
    u16* cfb = bfb;
    u16* xbf = bfb + RD;
    u16* qbf = bfb + 2 * RD;
    u16* kbf = bfb + 3 * RD;
    u16* vTb = bfb + 4 * RD;                        // [512,4096] (V transposed)
    u16* Wqb = bfb + 5 * RD;
    u16* Wkb = Wqb + 524288;
    u16* Wvb = Wkb + 524288;
    u16* W1b = Wvb + 524288;
    u16* W2b = W1b + 2097152;
    u16* Wsb = W2b + 2097152;

    const float scale = 0.044194173824159216f;      // 1/sqrt(512)

    ConvArgs ca;
    ca.src[0] = cf;  ca.dst[0] = cfb;
    ca.src[1] = Wq;  ca.dst[1] = Wqb;
    ca.src[2] = Wk;  ca.dst[2] = Wkb;
    ca.src[3] = Wv;  ca.dst[3] = Wvb;
    ca.src[4] = W1;  ca.dst[4] = W1b;
    ca.src[5] = W2;  ca.dst[5] = W2b;
    ca.src[6] = Wsg; ca.dst[6] = Wsb;
    ca.start[0] = 0;    ca.start[1] = 1024; ca.start[2] = 1280;
    ca.start[3] = 1536; ca.start[4] = 1792; ca.start[5] = 2816;
    ca.start[6] = 3840; ca.start[7] = 4096;
    conv_all<<<4096, 256, 0, stream>>>(ca);

    for (int l = 0; l < 2; ++l) {
        const u16* xa = (l == 0) ? cfb : xbf;
        qkv_gemm<<<dim3(64, 12), 256, 0, stream>>>(
            xa, cfb, Wqb + l * 262144, Wkb + l * 262144, Wvb + l * 262144,
            bq + l * 512, bk + l * 512, bv + l * 512, qbf, kbf, vTb);
        mgemm_tri<<<528, 256, 0, stream>>>(qbf, kbf, s, scale);
        softmax_pbf<<<4096, 256, 0, stream>>>(s, pbf, sums);
        // AV: split-K 4, balanced per row-block (s region dead -> partials alias)
        mgemm_pk<true><<<dim3(32, 4, 4), 256, 0, stream>>>(
            pbf, 4096, vTb, 4096, part, 4096, 0);
        ln_res_ps<4, false, true><<<1024, 256, 0, stream>>>(
            (l == 0) ? cf : x, part, nullptr, sums,
            ln1g + l * 512, ln1b + l * 512, x, xbf);
        mgemm<3><<<dim3(32, 16), 256, 0, stream>>>(
            xbf, 512, W1b + l * 1048576, 512, b1 + l * 2048, hbf, 2048, 512, 1.f);
        // MLP2: split-K 4 x 512
        mgemm_pk<false><<<dim3(32, 4, 4), 256, 0, stream>>>(
            hbf, 2048, W2b + l * 1048576, 2048, part, 2048, 512);
        ln_res_ps<4, true, false><<<1024, 256, 0, stream>>>(
            x, part, b2 + l * 512, nullptr,
            ln2g + l * 512, ln2b + l * 512, x, xbf);
    }

    build_cat<<<2048, 256, 0, stream>>>(catb, cfb, xbf);
    // gate: split-K 2 x 512
    mgemm_pk<false><<<dim3(32, 4, 2), 256, 0, stream>>>(
        catb, 1024, Wsb, 1024, part, 1024, 512);
    final_gate_ps<<<2048, 256, 0, stream>>>((float4*)out, (const float4*)cf,
                                            (const float4*)x, part, bsg);
}